// Round 2
// baseline (1681.173 us; speedup 1.0000x reference)
//
#include <hip/hip_runtime.h>
#include <hip/hip_fp16.h>

#define NB 8
#define CAP 128
#define NFEAT 704
#define MSLICE 16           // node slices per (batch,k) in moments
#define PSLICE (MSLICE * 4) // partial slots = slices * subs

// ---------------- setup kernels ----------------

__global__ void count_edges(const int* __restrict__ ei, int E, int* __restrict__ cnt) {
    int e = blockIdx.x * blockDim.x + threadIdx.x;
    if (e < E) atomicAdd(&cnt[ei[E + e]], 1);
}

__global__ void compute_dinv(const int* __restrict__ cnt, float* __restrict__ dinv, int n) {
    int v = blockIdx.x * blockDim.x + threadIdx.x;
    if (v < n) dinv[v] = rsqrtf((float)(cnt[v] + 1));  // +1 self-loop; always > 0
}

// packed edge: low 16 = src node (N < 65536), high 16 = f16 weight
__global__ void fill_edges(const int* __restrict__ ei, int E, const float* __restrict__ dinv,
                           int* __restrict__ cursor, unsigned int* __restrict__ pairs) {
    int e = blockIdx.x * blockDim.x + threadIdx.x;
    if (e < E) {
        int r = ei[e], c = ei[E + e];
        int pos = atomicAdd(&cursor[c], 1);
        if (pos < CAP) {
            float w = dinv[r] * dinv[c];
            __half hw = __float2half_rn(w);
            unsigned short hb = *reinterpret_cast<unsigned short*>(&hw);
            pairs[(size_t)c * CAP + pos] = (unsigned int)(r & 0xFFFF) | ((unsigned int)hb << 16);
        }
    }
}

// pad each node's edge list to a multiple of 16 with zero-weight edges (src 0, w +0)
__global__ void pad_edges(const int* __restrict__ cnt, unsigned int* __restrict__ pairs, int n) {
    int v = blockIdx.x * blockDim.x + threadIdx.x;
    if (v >= n) return;
    int c = min(cnt[v], CAP);
    int c16 = (c + 15) & ~15;
    for (int j = c; j < c16; ++j) pairs[(size_t)v * CAP + j] = 0u;
}

// batch is SORTED: boundaries, no atomics
__global__ void batch_bounds(const int* __restrict__ batch, int n, int* __restrict__ boff) {
    int i = blockIdx.x * blockDim.x + threadIdx.x;
    if (i >= n) return;
    int b = batch[i];
    int pb = (i == 0) ? -1 : batch[i - 1];
    for (int k = pb + 1; k <= b; ++k) boff[k] = i;
    if (i == n - 1) {
        for (int k = b + 1; k <= NB; ++k) boff[k] = n;
    }
}

// x [node][64] f32 -> channel-blocked xg [g][node][16] f32 + xh [g][node][16] f16
__global__ void blockify_x(const float* __restrict__ x, float* __restrict__ xg,
                           unsigned short* __restrict__ xh, int n) {
    int i = blockIdx.x * blockDim.x + threadIdx.x;
    if (i >= n * 64) return;
    int node = i >> 6, c = i & 63;
    float v = x[i];
    size_t o = (size_t)(c >> 4) * n * 16 + (size_t)node * 16 + (c & 15);
    xg[o] = v;
    __half h = __float2half_rn(v);
    xh[o] = *reinterpret_cast<unsigned short*>(&h);
}

// ---------------- cascade: channel-split, XCD-affine ----------------
// All state/mirror arrays are channel-blocked [g][node][16] (units prepended
// as [u][g][node][16]). Block mapping: g = (bid&7)>>1 so each channel group
// lives on a fixed pair of XCDs (blockIdx%8 round-robin heuristic) -> per-XCD
// gather working set = 4 units x 0.64 MB = 2.56 MB < 4 MB L2.
// Lane layout: sub = lane>>2 (16 edge phases/iter), cg = lane&3 (4-chan quad,
// uint2 gather = 8 B). Pairs loaded per-lane (dword, nontemporal: streamed,
// don't evict mirrors), next group's pair prefetched before current gathers.
// h_out = 0.5*((1+dinv^2)*h_in + sum w*h_in[src]); gathers fp16, rest fp32.
// L1 snap s=1, diffs {2,4,8,16}->S1 slots 0..3 (+f16 S1h slots 0..2).
// L2 unit u: snap s=2<<u, diffs later {4,8,16}->S2 slots (FENG order).

__device__ __forceinline__ float h2f16(unsigned short h) {
    __half hh = *reinterpret_cast<__half*>(&h);
    return __half2float(hh);
}

__device__ __forceinline__ void fma_h4(float w, uint2 m, float* a) {
    float2 f0 = __half22float2(*reinterpret_cast<__half2*>(&m.x));
    float2 f1 = __half22float2(*reinterpret_cast<__half2*>(&m.y));
    a[0] += w * f0.x; a[1] += w * f0.y; a[2] += w * f1.x; a[3] += w * f1.y;
}

__device__ __forceinline__ uint2 pack_h4(float4 v) {
    __half2 p01 = __float22half2_rn(make_float2(v.x, v.y));
    __half2 p23 = __float22half2_rn(make_float2(v.z, v.w));
    uint2 r;
    r.x = *reinterpret_cast<unsigned int*>(&p01);
    r.y = *reinterpret_cast<unsigned int*>(&p23);
    return r;
}

template <int U1, int U2>
__global__ __launch_bounds__(256) void cascade_k(
    const float* __restrict__ self1, const unsigned short* __restrict__ mir1,
    float* __restrict__ state1o, unsigned short* __restrict__ mir1o,
    float* __restrict__ prev1, int s1,
    const float* __restrict__ self2, int sstride2, long usz2, long gsz2,
    const unsigned short* __restrict__ mir2, long musz2,
    float* __restrict__ state2o, unsigned short* __restrict__ mir2o,
    float* __restrict__ prev2, int s2,
    const unsigned int* __restrict__ pairs, const int* __restrict__ cnt,
    const float* __restrict__ dinv, int n,
    float* __restrict__ S1, unsigned short* __restrict__ S1h,
    float* __restrict__ S2)
{
    int lane = threadIdx.x & 63, widx = threadIdx.x >> 6;
    int bid = blockIdx.x;
    int g = (bid >> 1) & 3;                 // channel group -> XCD pair {2g,2g+1}
    int quad = (bid >> 3) * 2 + (bid & 1);  // node quad within group
    int node = quad * 4 + widx;
    if (node >= n) return;
    node = __builtin_amdgcn_readfirstlane(node);

    int deg = min(cnt[node], CAP);
    int deg16 = (deg + 15) & ~15;
    float dv = dinv[node];
    float selfw = 1.f + dv * dv;

    int sub = lane >> 2;   // edge within group of 16
    int cg  = lane & 3;    // channel quad within the 16-chan slice
    size_t goff = (size_t)g * n * 16;

    const unsigned int* pb = pairs + (size_t)node * CAP;

    float a1[4], a2[U2 ? U2 : 1][4];
#pragma unroll
    for (int k = 0; k < 4; ++k) a1[k] = 0.f;
#pragma unroll
    for (int u = 0; u < (U2 ? U2 : 1); ++u)
#pragma unroll
        for (int k = 0; k < 4; ++k) a2[u][k] = 0.f;

    if (deg16 > 0) {
        unsigned int e = __builtin_nontemporal_load(pb + sub);
        int j = 0;
        while (true) {
            int jn = j + 16;
            bool more = jn < deg16;
            unsigned int en = 0;
            if (more) en = __builtin_nontemporal_load(pb + jn + sub);  // prefetch
            int   s = (int)(e & 0xFFFFu);
            float w = h2f16((unsigned short)(e >> 16));
            size_t ro = goff + (size_t)s * 16 + cg * 4;
            // issue all gathers, then all FMAs
            uint2 g1, g2[U2 ? U2 : 1];
            if (U1) g1 = *reinterpret_cast<const uint2*>(mir1 + ro);
#pragma unroll
            for (int u = 0; u < U2; ++u)
                g2[u] = *reinterpret_cast<const uint2*>(mir2 + (size_t)u * musz2 + ro);
            if (U1) fma_h4(w, g1, a1);
#pragma unroll
            for (int u = 0; u < U2; ++u) fma_h4(w, g2[u], a2[u]);
            if (!more) break;
            e = en; j = jn;
        }
    }

    // reduce the 16 edge-phases: lanes {cg, cg+4, ..., cg+60} share channels
#pragma unroll
    for (int m = 4; m <= 32; m <<= 1) {
        if (U1)
#pragma unroll
            for (int k = 0; k < 4; ++k) a1[k] += __shfl_xor(a1[k], m, 64);
#pragma unroll
        for (int u = 0; u < U2; ++u)
#pragma unroll
            for (int k = 0; k < 4; ++k) a2[u][k] += __shfl_xor(a2[u][k], m, 64);
    }

    if (lane < 4) {
        size_t base = goff + (size_t)node * 16 + cg * 4;
        if (U1) {
            float4 hv = *reinterpret_cast<const float4*>(self1 + base);
            float4 v;
            v.x = 0.5f * (selfw * hv.x + a1[0]);
            v.y = 0.5f * (selfw * hv.y + a1[1]);
            v.z = 0.5f * (selfw * hv.z + a1[2]);
            v.w = 0.5f * (selfw * hv.w + a1[3]);
            *reinterpret_cast<float4*>(state1o + base) = v;
            *reinterpret_cast<uint2*>(mir1o + base) = pack_h4(v);
            float* prow = prev1 + base;
            if (s1 == 1) {
                *reinterpret_cast<float4*>(prow) = v;
            } else if (s1 == 2 || s1 == 4 || s1 == 8 || s1 == 16) {
                float4 pv = *reinterpret_cast<const float4*>(prow);
                *reinterpret_cast<float4*>(prow) = v;
                float4 d;
                d.x = fabsf(v.x - pv.x); d.y = fabsf(v.y - pv.y);
                d.z = fabsf(v.z - pv.z); d.w = fabsf(v.w - pv.w);
                int slot = (s1 == 2) ? 0 : (s1 == 4) ? 1 : (s1 == 8) ? 2 : 3;
                *reinterpret_cast<float4*>(S1 + (size_t)g * n * 64 + (size_t)node * 64 + slot * 16 + cg * 4) = d;
                if (slot < 3)
                    *reinterpret_cast<uint2*>(S1h + (size_t)slot * n * 64 + base) = pack_h4(d);
            }
        }
#pragma unroll
        for (int u = 0; u < U2; ++u) {
            const float* srow = self2 + (size_t)u * usz2 + (size_t)g * gsz2
                              + (size_t)node * sstride2 + cg * 4;
            float4 hv = *reinterpret_cast<const float4*>(srow);
            float4 v;
            v.x = 0.5f * (selfw * hv.x + a2[u][0]);
            v.y = 0.5f * (selfw * hv.y + a2[u][1]);
            v.z = 0.5f * (selfw * hv.z + a2[u][2]);
            v.w = 0.5f * (selfw * hv.w + a2[u][3]);
            size_t oidx = (size_t)u * n * 64 + base;
            *reinterpret_cast<float4*>(state2o + oidx) = v;
            *reinterpret_cast<uint2*>(mir2o + oidx) = pack_h4(v);
            int snap = 2 << u;
            float* prow = prev2 + oidx;
            if (s2 == snap) {
                *reinterpret_cast<float4*>(prow) = v;
            } else if (s2 > snap && (s2 == 4 || s2 == 8 || s2 == 16)) {
                float4 pv = *reinterpret_cast<const float4*>(prow);
                *reinterpret_cast<float4*>(prow) = v;
                float4 d;
                d.x = fabsf(v.x - pv.x); d.y = fabsf(v.y - pv.y);
                d.z = fabsf(v.z - pv.z); d.w = fabsf(v.w - pv.w);
                int slt;
                if (u == 0)      slt = (s2 == 4) ? 0 : (s2 == 8) ? 1 : 3;
                else if (u == 1) slt = (s2 == 8) ? 2 : 4;
                else             slt = 5;
                *reinterpret_cast<float4*>(S2 + (size_t)g * n * 96 + (size_t)node * 96 + slt * 16 + cg * 4) = d;
            }
        }
    }
}

// ---------------- moments (coalesced two-stage, no atomics) ----------------

__global__ __launch_bounds__(256) void moments_part(
    const float* __restrict__ xg, const float* __restrict__ S1,
    const float* __restrict__ S2, const int* __restrict__ boff,
    double* __restrict__ part, int n)
{
    int bid = blockIdx.x;                    // b * (11*MSLICE) + k * MSLICE + slice
    int slice = bid % MSLICE;
    int k = (bid / MSLICE) % 11;
    int b = bid / (11 * MSLICE);
    int c = threadIdx.x & 63, sub = threadIdx.x >> 6;
    int g = c >> 4, off = c & 15;

    const float* base; int stride;
    if (k == 0)      { base = xg + (size_t)g * n * 16 + off;                 stride = 16; }
    else if (k <= 4) { base = S1 + (size_t)g * n * 64 + (k - 1) * 16 + off;  stride = 64; }
    else             { base = S2 + (size_t)g * n * 96 + (k - 5) * 16 + off;  stride = 96; }

    int s0 = boff[b], s1e = boff[b + 1];
    int cntb = s1e - s0;
    int per = (cntb + MSLICE - 1) / MSLICE;
    int i0 = s0 + slice * per;
    int i1 = min(s1e, i0 + per);

    double a1 = 0, a2 = 0, a3 = 0, a4 = 0;
    for (int i = i0 + sub; i < i1; i += 4) {
        double v = (double)base[(size_t)i * stride];
        double qq = v * v;
        a1 += v; a2 += qq; a3 += qq * v; a4 += qq * qq;
    }
    int f = k * 64 + c;
    double* qp = part + ((((size_t)slice * 4 + sub) * NB + b) * NFEAT + f) * 4;
    qp[0] = a1; qp[1] = a2; qp[2] = a3; qp[3] = a4;
}

__global__ void finalize_k(const double* __restrict__ part, const int* __restrict__ boff,
                           const float* __restrict__ W, float* __restrict__ out) {
    int i = blockIdx.x * blockDim.x + threadIdx.x;
    if (i < NB * NFEAT) {
        int b = i / NFEAT, f = i % NFEAT;
        double s1 = 0, s2 = 0, s3 = 0, s4 = 0;
        for (int s = 0; s < PSLICE; ++s) {
            const double* qp = part + (((size_t)s * NB + b) * NFEAT + f) * 4;
            s1 += qp[0]; s2 += qp[1]; s3 += qp[2]; s4 += qp[3];
        }
        double cn = (double)max(boff[b + 1] - boff[b], 1);
        double mean = s1 / cn;
        double e2 = s2 / cn, e3 = s3 / cn, e4 = s4 / cn;
        double var = e2 - mean * mean;
        double m3 = e3 - 3.0 * mean * e2 + 2.0 * mean * mean * mean;
        double m4 = e4 - 4.0 * mean * e3 + 6.0 * mean * mean * e2 - 3.0 * mean * mean * mean * mean;
        float skew, kurt;
        if (var > 0.0) {
            double vs = var * sqrt(var);
            skew = (float)(m3 / vs);
            kurt = (float)(m4 / (var * var));
        } else {
            skew = 0.f; kurt = -3.f;
        }
        out[b * 2816 + f]        = (float)mean;
        out[b * 2816 + 704 + f]  = (float)var;
        out[b * 2816 + 1408 + f] = skew;
        out[b * 2816 + 2112 + f] = kurt;
    } else if (i < NB * NFEAT + 68) {
        int j = i - NB * NFEAT;
        out[NB * 2816 + j] = W[j];
    }
}

// ---------------- launch ----------------

extern "C" void kernel_launch(void* const* d_in, const int* in_sizes, int n_in,
                              void* d_out, int out_size, void* d_ws, size_t ws_size,
                              hipStream_t stream) {
    const float* x     = (const float*)d_in[0];
    const int*   ei    = (const int*)d_in[1];
    const int*   batch = (const int*)d_in[2];
    const float* W     = (const float*)d_in[3];
    int N = in_sizes[0] / 64;   // 20000
    int E = in_sizes[1] / 2;    // 640000
    float* out = (float*)d_out;

    char* p = (char*)d_ws;
    auto alloc = [&](size_t bytes) { char* r = p; p += (bytes + 255) & ~255ULL; return r; };
    float* dinv  = (float*)alloc((size_t)N * 4);
    int*   cnt   = (int*)alloc((size_t)N * 4);
    int*   cursor= (int*)alloc((size_t)N * 4);
    int*   boff  = (int*)alloc((NB + 1) * 4);
    double* part = (double*)alloc((size_t)PSLICE * NB * NFEAT * 4 * 8);
    unsigned int* pairs = (unsigned int*)alloc((size_t)N * CAP * 4);
    float* S1    = (float*)alloc((size_t)N * 256 * 4);
    float* S2    = (float*)alloc((size_t)N * 384 * 4);
    unsigned short* S1h = (unsigned short*)alloc((size_t)3 * N * 64 * 2);
    float* xg    = (float*)alloc((size_t)N * 64 * 4);
    unsigned short* xh  = (unsigned short*)alloc((size_t)N * 64 * 2);
    float* b1A   = (float*)alloc((size_t)N * 64 * 4);
    float* b1B   = (float*)alloc((size_t)N * 64 * 4);
    unsigned short* h1A = (unsigned short*)alloc((size_t)N * 64 * 2);
    unsigned short* h1B = (unsigned short*)alloc((size_t)N * 64 * 2);
    float* prev1 = (float*)alloc((size_t)N * 64 * 4);
    float* b2A   = (float*)alloc((size_t)3 * N * 64 * 4);
    float* b2B   = (float*)alloc((size_t)3 * N * 64 * 4);
    unsigned short* h2A = (unsigned short*)alloc((size_t)3 * N * 64 * 2);
    unsigned short* h2B = (unsigned short*)alloc((size_t)3 * N * 64 * 2);
    float* prev2 = (float*)alloc((size_t)3 * N * 64 * 4);

    hipMemsetAsync(cnt, 0, (size_t)N * 4, stream);
    hipMemsetAsync(cursor, 0, (size_t)N * 4, stream);

    count_edges<<<(E + 255) / 256, 256, 0, stream>>>(ei, E, cnt);
    compute_dinv<<<(N + 255) / 256, 256, 0, stream>>>(cnt, dinv, N);
    fill_edges<<<(E + 255) / 256, 256, 0, stream>>>(ei, E, dinv, cursor, pairs);
    pad_edges<<<(N + 255) / 256, 256, 0, stream>>>(cnt, pairs, N);
    batch_bounds<<<(N + 255) / 256, 256, 0, stream>>>(batch, N, boff);
    blockify_x<<<(N * 64 + 255) / 256, 256, 0, stream>>>(x, xg, xh, N);

    long nu = (long)N * 64;
    int quads = (N + 3) / 4;
    int cgrid = ((quads + 1) / 2) * 8;   // 4 channel groups x 2 XCD slots each

    // ---- phase A: L1 steps 1..8 (snap s=1; diffs s=2,4,8 -> S1 slots 0..2 + S1h) ----
    for (int s = 1; s <= 8; ++s) {
        const float* si = (s == 1) ? xg : ((s & 1) ? b1B : b1A);
        const unsigned short* mi = (s == 1) ? xh : ((s & 1) ? h1B : h1A);
        float* so = (s & 1) ? b1A : b1B;
        unsigned short* mo = (s & 1) ? h1A : h1B;
        cascade_k<1, 0><<<cgrid, 256, 0, stream>>>(
            si, mi, so, mo, prev1, s,
            nullptr, 0, 0, 0, nullptr, 0, nullptr, nullptr, nullptr, 0,
            pairs, cnt, dinv, N, S1, S1h, S2);
    }

    // ---- phase B: fused — L1 step t=f+8 with L2 step f, f=1..8 ----
    for (int f = 1; f <= 8; ++f) {
        int t = f + 8;
        const float* s1i = ((t - 1) & 1) ? b1A : b1B;
        const unsigned short* m1i = ((t - 1) & 1) ? h1A : h1B;
        float* s1o = (t & 1) ? b1A : b1B;
        unsigned short* m1o = (t & 1) ? h1A : h1B;
        const float* s2i; int sstride2; long usz2, gsz2;
        const unsigned short* m2i; long musz2;
        if (f == 1) {
            s2i = S1; sstride2 = 64; usz2 = 16; gsz2 = (long)N * 64;
            m2i = S1h; musz2 = nu;
        } else {
            s2i = ((f - 1) & 1) ? b2A : b2B; sstride2 = 16; usz2 = nu; gsz2 = (long)N * 16;
            m2i = ((f - 1) & 1) ? h2A : h2B; musz2 = nu;
        }
        float* s2o = (f & 1) ? b2A : b2B;
        unsigned short* m2o = (f & 1) ? h2A : h2B;
        cascade_k<1, 3><<<cgrid, 256, 0, stream>>>(
            s1i, m1i, s1o, m1o, prev1, t,
            s2i, sstride2, usz2, gsz2, m2i, musz2, s2o, m2o, prev2, f,
            pairs, cnt, dinv, N, S1, S1h, S2);
    }

    // ---- phase C: L2-only steps 9..16 (diffs at 16 -> S2 slots 3,4,5) ----
    for (int s = 9; s <= 16; ++s) {
        const float* s2i = ((s - 1) & 1) ? b2A : b2B;
        const unsigned short* m2i = ((s - 1) & 1) ? h2A : h2B;
        float* s2o = (s & 1) ? b2A : b2B;
        unsigned short* m2o = (s & 1) ? h2A : h2B;
        cascade_k<0, 3><<<cgrid, 256, 0, stream>>>(
            nullptr, nullptr, nullptr, nullptr, nullptr, 0,
            s2i, 16, nu, (long)N * 16, m2i, nu, s2o, m2o, prev2, s,
            pairs, cnt, dinv, N, S1, S1h, S2);
    }

    moments_part<<<NB * 11 * MSLICE, 256, 0, stream>>>(xg, S1, S2, boff, part, N);

    int fin_threads = NB * NFEAT + 68;
    finalize_k<<<(fin_threads + 255) / 256, 256, 0, stream>>>(part, boff, W, out);
}

// Round 3
// 1150.193 us; speedup vs baseline: 1.4616x; 1.4616x over previous
//
#include <hip/hip_runtime.h>
#include <hip/hip_fp16.h>

#define NB 8
#define CAP 128
#define NFEAT 704
#define MSLICE 16           // node slices per (batch,k) in moments
#define PSLICE (MSLICE * 4) // partial slots = slices * subs

// ---------------- setup kernels ----------------

__global__ void count_edges(const int* __restrict__ ei, int E, int* __restrict__ cnt) {
    int e = blockIdx.x * blockDim.x + threadIdx.x;
    if (e < E) atomicAdd(&cnt[ei[E + e]], 1);
}

__global__ void compute_dinv(const int* __restrict__ cnt, float* __restrict__ dinv, int n) {
    int v = blockIdx.x * blockDim.x + threadIdx.x;
    if (v < n) dinv[v] = rsqrtf((float)(cnt[v] + 1));  // +1 self-loop; always > 0
}

// packed edge: low 16 = src node (N < 65536), high 16 = f16 weight
__global__ void fill_edges(const int* __restrict__ ei, int E, const float* __restrict__ dinv,
                           int* __restrict__ cursor, unsigned int* __restrict__ pairs) {
    int e = blockIdx.x * blockDim.x + threadIdx.x;
    if (e < E) {
        int r = ei[e], c = ei[E + e];
        int pos = atomicAdd(&cursor[c], 1);
        if (pos < CAP) {
            float w = dinv[r] * dinv[c];
            __half hw = __float2half_rn(w);
            unsigned short hb = *reinterpret_cast<unsigned short*>(&hw);
            pairs[(size_t)c * CAP + pos] = (unsigned int)(r & 0xFFFF) | ((unsigned int)hb << 16);
        }
    }
}

// pad each node's edge list to a multiple of 8 with zero-weight edges (src 0, w +0)
__global__ void pad_edges(const int* __restrict__ cnt, unsigned int* __restrict__ pairs, int n) {
    int v = blockIdx.x * blockDim.x + threadIdx.x;
    if (v >= n) return;
    int c = min(cnt[v], CAP);
    int c8 = (c + 7) & ~7;
    for (int j = c; j < c8; ++j) pairs[(size_t)v * CAP + j] = 0u;
}

// batch is SORTED: boundaries, no atomics
__global__ void batch_bounds(const int* __restrict__ batch, int n, int* __restrict__ boff) {
    int i = blockIdx.x * blockDim.x + threadIdx.x;
    if (i >= n) return;
    int b = batch[i];
    int pb = (i == 0) ? -1 : batch[i - 1];
    for (int k = pb + 1; k <= b; ++k) boff[k] = i;
    if (i == n - 1) {
        for (int k = b + 1; k <= NB; ++k) boff[k] = n;
    }
}

__global__ void convert_f16(const float* __restrict__ x, unsigned short* __restrict__ xh, int n) {
    int i = blockIdx.x * blockDim.x + threadIdx.x;
    if (i < n) {
        __half h = __float2half_rn(x[i]);
        xh[i] = *reinterpret_cast<unsigned short*>(&h);
    }
}

// ---------------- nontemporal helpers (protect resident gather mirror in L2) ----

typedef unsigned int  u32x4 __attribute__((ext_vector_type(4)));
typedef unsigned int  u32x2 __attribute__((ext_vector_type(2)));
typedef float         f32x4 __attribute__((ext_vector_type(4)));

__device__ __forceinline__ uint4 ntload_u4(const unsigned int* p) {
    u32x4 t = __builtin_nontemporal_load(reinterpret_cast<const u32x4*>(p));
    uint4 v; v.x = t.x; v.y = t.y; v.z = t.z; v.w = t.w; return v;
}
__device__ __forceinline__ float4 ntload_f4(const float* p) {
    f32x4 t = __builtin_nontemporal_load(reinterpret_cast<const f32x4*>(p));
    return make_float4(t.x, t.y, t.z, t.w);
}
__device__ __forceinline__ void ntstore_f4(float* p, float4 v) {
    f32x4 t; t.x = v.x; t.y = v.y; t.z = v.z; t.w = v.w;
    __builtin_nontemporal_store(t, reinterpret_cast<f32x4*>(p));
}
__device__ __forceinline__ void ntstore_u2(unsigned short* p, uint2 v) {
    u32x2 t; t.x = v.x; t.y = v.y;
    __builtin_nontemporal_store(t, reinterpret_cast<u32x2*>(p));
}

__device__ __forceinline__ float h2f16(unsigned short h) {
    __half hh = *reinterpret_cast<__half*>(&h);
    return __half2float(hh);
}

__device__ __forceinline__ void fma_h4(float w, uint2 m, float* a) {
    float2 f0 = __half22float2(*reinterpret_cast<__half2*>(&m.x));
    float2 f1 = __half22float2(*reinterpret_cast<__half2*>(&m.y));
    a[0] += w * f0.x; a[1] += w * f0.y; a[2] += w * f1.x; a[3] += w * f1.y;
}

__device__ __forceinline__ uint2 pack_h4(float4 v) {
    __half2 p01 = __float22half2_rn(make_float2(v.x, v.y));
    __half2 p23 = __float22half2_rn(make_float2(v.z, v.w));
    uint2 r;
    r.x = *reinterpret_cast<unsigned int*>(&p01);
    r.y = *reinterpret_cast<unsigned int*>(&p23);
    return r;
}

// ---------------- cascade: one UNIT per block, XCD-affine by unit ----------------
// MODE 0 (phase A): all blocks run the L1 unit; quad = bid; grid = ceil(N/4).
// MODE 1 (phase B): role = (bid&7)>>1; role 0 -> L1 step, roles 1..3 -> L2 unit r-1.
//   Each role's blocks land on one XCD pair (blockIdx%8 round-robin), so each
//   XCD gathers from exactly ONE 2.56 MB fp16 mirror -> L2-resident; mirror
//   written by a role is re-read by the same role next step -> dirty-line L2 hits.
// MODE 2 (phase C): 3 L2 units on XCD slots {0,1,2}->u0 {3,4,5}->u1 {6,7}->u2.
// Gathers keep the full-row layout: sub=lane>>4 (4 edge phases), cg=lane&15
// (16 channel quads) -> 16 lanes x uint2 = one 128 B line per edge per unit.
// All 1-touch streams (pairs/self/prev/state/S1/S2/S1h) are nontemporal so the
// gather mirror stays resident; mirror OUTPUT stores are normal (next step's
// gather source, same XCD pair).
// h_out = 0.5*((1+dinv^2)*h_in + sum w*h_in[src]); gathers fp16, rest fp32.
// L1 snap s=1, diffs {2,4,8,16}->S1 slots 0..3 (+f16 S1h slots 0..2).
// L2 unit u: snap s=2<<u, diffs later {4,8,16}->S2 slots (FENG order).

template <int MODE>
__global__ __launch_bounds__(256) void cascade1_k(
    const float* __restrict__ self1, const unsigned short* __restrict__ mir1,
    float* __restrict__ state1o, unsigned short* __restrict__ mir1o,
    float* __restrict__ prev1, int s1,
    const float* __restrict__ self2, int sstride2, long usz2,
    const unsigned short* __restrict__ mir2, long musz2,
    float* __restrict__ state2o, unsigned short* __restrict__ mir2o,
    float* __restrict__ prev2, int s2,
    const unsigned int* __restrict__ pairs, const int* __restrict__ cnt,
    const float* __restrict__ dinv, int n,
    float* __restrict__ S1, unsigned short* __restrict__ S1h,
    float* __restrict__ S2)
{
    int lane = threadIdx.x & 63, widx = threadIdx.x >> 6;
    int bid = blockIdx.x;
    int quad, r;
    if (MODE == 0) {
        quad = bid; r = 0;
    } else if (MODE == 1) {
        int s = bid & 7;
        r = s >> 1;                              // 4 roles x 2 XCD slots
        quad = (bid >> 3) * 2 + (s & 1);
    } else {
        int s = bid & 7;                         // {3,3,2} XCD slots per unit
        r = (s < 3) ? 0 : (s < 6) ? 1 : 2;
        int ls = s - ((r == 0) ? 0 : (r == 1) ? 3 : 6);
        int ns = (r == 2) ? 2 : 3;
        quad = (bid >> 3) * ns + ls;
    }
    int node = quad * 4 + widx;
    if (node >= n) return;
    node = __builtin_amdgcn_readfirstlane(node);

    bool isL1 = (MODE == 0) || (MODE == 1 && r == 0);
    int u = (MODE == 1) ? (r - 1) : r;           // valid only when !isL1

    int deg = min(cnt[node], CAP);
    int deg8 = (deg + 7) & ~7;
    float dv = dinv[node];
    float selfw = 1.f + dv * dv;

    int sub = lane >> 4;   // edge within group of 4
    int cg  = lane & 15;   // channel quad: ch cg*4 .. +3

    const unsigned int* pb = pairs + (size_t)node * CAP;
    const unsigned short* gm = isL1 ? mir1 : (mir2 + (size_t)u * musz2);

    float a[4] = {0.f, 0.f, 0.f, 0.f};

    if (deg8 > 0) {
        uint4 qA = ntload_u4(pb);
        uint4 qB = ntload_u4(pb + 4);
        int j = 0;
        while (true) {
            int jn = j + 8;
            bool more = jn < deg8;
            uint4 nA, nB;
            if (more) {  // prefetch next pair group before consuming this one
                nA = ntload_u4(pb + jn);
                nB = ntload_u4(pb + jn + 4);
            }
            unsigned int eA = sub < 2 ? (sub == 0 ? qA.x : qA.y) : (sub == 2 ? qA.z : qA.w);
            unsigned int eB = sub < 2 ? (sub == 0 ? qB.x : qB.y) : (sub == 2 ? qB.z : qB.w);
            int   sA = (int)(eA & 0xFFFFu);
            float wA = h2f16((unsigned short)(eA >> 16));
            int   sB = (int)(eB & 0xFFFFu);
            float wB = h2f16((unsigned short)(eB >> 16));
            uint2 gA = *reinterpret_cast<const uint2*>(gm + (size_t)sA * 64 + cg * 4);
            uint2 gB = *reinterpret_cast<const uint2*>(gm + (size_t)sB * 64 + cg * 4);
            fma_h4(wA, gA, a);
            fma_h4(wB, gB, a);
            if (!more) break;
            qA = nA; qB = nB; j = jn;
        }
    }

    // reduce the 4 edge-phases: lanes {cg, cg+16, cg+32, cg+48} share channels
#pragma unroll
    for (int m = 16; m <= 32; m <<= 1)
#pragma unroll
        for (int k = 0; k < 4; ++k) a[k] += __shfl_xor(a[k], m, 64);

    if (lane < 16) {
        if (isL1) {
            size_t oidx = (size_t)node * 64 + cg * 4;
            float4 hv = ntload_f4(self1 + oidx);
            float4 v;
            v.x = 0.5f * (selfw * hv.x + a[0]);
            v.y = 0.5f * (selfw * hv.y + a[1]);
            v.z = 0.5f * (selfw * hv.z + a[2]);
            v.w = 0.5f * (selfw * hv.w + a[3]);
            ntstore_f4(state1o + oidx, v);
            *reinterpret_cast<uint2*>(mir1o + oidx) = pack_h4(v);  // gather src next step
            float* prow = prev1 + oidx;
            if (s1 == 1) {
                ntstore_f4(prow, v);
            } else if (s1 == 2 || s1 == 4 || s1 == 8 || s1 == 16) {
                float4 pv = ntload_f4(prow);
                ntstore_f4(prow, v);
                float4 d;
                d.x = fabsf(v.x - pv.x); d.y = fabsf(v.y - pv.y);
                d.z = fabsf(v.z - pv.z); d.w = fabsf(v.w - pv.w);
                int slot = (s1 == 2) ? 0 : (s1 == 4) ? 1 : (s1 == 8) ? 2 : 3;
                ntstore_f4(S1 + (size_t)node * 256 + slot * 64 + cg * 4, d);
                if (slot < 3)
                    ntstore_u2(S1h + (size_t)slot * n * 64 + oidx, pack_h4(d));
            }
        } else {
            const float* srow = self2 + (size_t)u * usz2 + (size_t)node * sstride2 + cg * 4;
            float4 hv = ntload_f4(srow);
            float4 v;
            v.x = 0.5f * (selfw * hv.x + a[0]);
            v.y = 0.5f * (selfw * hv.y + a[1]);
            v.z = 0.5f * (selfw * hv.z + a[2]);
            v.w = 0.5f * (selfw * hv.w + a[3]);
            size_t oidx = (size_t)u * n * 64 + (size_t)node * 64 + cg * 4;
            ntstore_f4(state2o + oidx, v);
            *reinterpret_cast<uint2*>(mir2o + oidx) = pack_h4(v);  // gather src next step
            int snap = 2 << u;
            float* prow = prev2 + oidx;
            if (s2 == snap) {
                ntstore_f4(prow, v);
            } else if (s2 > snap && (s2 == 4 || s2 == 8 || s2 == 16)) {
                float4 pv = ntload_f4(prow);
                ntstore_f4(prow, v);
                float4 d;
                d.x = fabsf(v.x - pv.x); d.y = fabsf(v.y - pv.y);
                d.z = fabsf(v.z - pv.z); d.w = fabsf(v.w - pv.w);
                int slt;
                if (u == 0)      slt = (s2 == 4) ? 0 : (s2 == 8) ? 1 : 3;
                else if (u == 1) slt = (s2 == 8) ? 2 : 4;
                else             slt = 5;
                ntstore_f4(S2 + (size_t)node * 384 + slt * 64 + cg * 4, d);
            }
        }
    }
}

// ---------------- moments (coalesced two-stage, no atomics) ----------------

__global__ __launch_bounds__(256) void moments_part(
    const float* __restrict__ x, const float* __restrict__ S1,
    const float* __restrict__ S2, const int* __restrict__ boff,
    double* __restrict__ part)
{
    int bid = blockIdx.x;                    // b * (11*MSLICE) + k * MSLICE + slice
    int slice = bid % MSLICE;
    int k = (bid / MSLICE) % 11;
    int b = bid / (11 * MSLICE);
    int c = threadIdx.x & 63, sub = threadIdx.x >> 6;

    const float* base; int stride;
    if (k == 0)      { base = x  + c;                stride = 64;  }
    else if (k <= 4) { base = S1 + (k - 1) * 64 + c; stride = 256; }
    else             { base = S2 + (k - 5) * 64 + c; stride = 384; }

    int s0 = boff[b], s1e = boff[b + 1];
    int cntb = s1e - s0;
    int per = (cntb + MSLICE - 1) / MSLICE;
    int i0 = s0 + slice * per;
    int i1 = min(s1e, i0 + per);

    double a1 = 0, a2 = 0, a3 = 0, a4 = 0;
    for (int i = i0 + sub; i < i1; i += 4) {
        double v = (double)base[(size_t)i * stride];
        double qq = v * v;
        a1 += v; a2 += qq; a3 += qq * v; a4 += qq * qq;
    }
    int f = k * 64 + c;
    double* qp = part + ((((size_t)slice * 4 + sub) * NB + b) * NFEAT + f) * 4;
    qp[0] = a1; qp[1] = a2; qp[2] = a3; qp[3] = a4;
}

__global__ void finalize_k(const double* __restrict__ part, const int* __restrict__ boff,
                           const float* __restrict__ W, float* __restrict__ out) {
    int i = blockIdx.x * blockDim.x + threadIdx.x;
    if (i < NB * NFEAT) {
        int b = i / NFEAT, f = i % NFEAT;
        double s1 = 0, s2 = 0, s3 = 0, s4 = 0;
        for (int s = 0; s < PSLICE; ++s) {
            const double* qp = part + (((size_t)s * NB + b) * NFEAT + f) * 4;
            s1 += qp[0]; s2 += qp[1]; s3 += qp[2]; s4 += qp[3];
        }
        double cn = (double)max(boff[b + 1] - boff[b], 1);
        double mean = s1 / cn;
        double e2 = s2 / cn, e3 = s3 / cn, e4 = s4 / cn;
        double var = e2 - mean * mean;
        double m3 = e3 - 3.0 * mean * e2 + 2.0 * mean * mean * mean;
        double m4 = e4 - 4.0 * mean * e3 + 6.0 * mean * mean * e2 - 3.0 * mean * mean * mean * mean;
        float skew, kurt;
        if (var > 0.0) {
            double vs = var * sqrt(var);
            skew = (float)(m3 / vs);
            kurt = (float)(m4 / (var * var));
        } else {
            skew = 0.f; kurt = -3.f;
        }
        out[b * 2816 + f]        = (float)mean;
        out[b * 2816 + 704 + f]  = (float)var;
        out[b * 2816 + 1408 + f] = skew;
        out[b * 2816 + 2112 + f] = kurt;
    } else if (i < NB * NFEAT + 68) {
        int j = i - NB * NFEAT;
        out[NB * 2816 + j] = W[j];
    }
}

// ---------------- launch ----------------

extern "C" void kernel_launch(void* const* d_in, const int* in_sizes, int n_in,
                              void* d_out, int out_size, void* d_ws, size_t ws_size,
                              hipStream_t stream) {
    const float* x     = (const float*)d_in[0];
    const int*   ei    = (const int*)d_in[1];
    const int*   batch = (const int*)d_in[2];
    const float* W     = (const float*)d_in[3];
    int N = in_sizes[0] / 64;   // 20000
    int E = in_sizes[1] / 2;    // 640000
    float* out = (float*)d_out;

    char* p = (char*)d_ws;
    auto alloc = [&](size_t bytes) { char* r = p; p += (bytes + 255) & ~255ULL; return r; };
    float* dinv  = (float*)alloc((size_t)N * 4);
    int*   cnt   = (int*)alloc((size_t)N * 4);
    int*   cursor= (int*)alloc((size_t)N * 4);
    int*   boff  = (int*)alloc((NB + 1) * 4);
    double* part = (double*)alloc((size_t)PSLICE * NB * NFEAT * 4 * 8);
    unsigned int* pairs = (unsigned int*)alloc((size_t)N * CAP * 4);
    float* S1    = (float*)alloc((size_t)N * 256 * 4);
    float* S2    = (float*)alloc((size_t)N * 384 * 4);
    unsigned short* S1h = (unsigned short*)alloc((size_t)3 * N * 64 * 2);
    unsigned short* xh  = (unsigned short*)alloc((size_t)N * 64 * 2);
    float* b1A   = (float*)alloc((size_t)N * 64 * 4);
    float* b1B   = (float*)alloc((size_t)N * 64 * 4);
    unsigned short* h1A = (unsigned short*)alloc((size_t)N * 64 * 2);
    unsigned short* h1B = (unsigned short*)alloc((size_t)N * 64 * 2);
    float* prev1 = (float*)alloc((size_t)N * 64 * 4);
    float* b2A   = (float*)alloc((size_t)3 * N * 64 * 4);
    float* b2B   = (float*)alloc((size_t)3 * N * 64 * 4);
    unsigned short* h2A = (unsigned short*)alloc((size_t)3 * N * 64 * 2);
    unsigned short* h2B = (unsigned short*)alloc((size_t)3 * N * 64 * 2);
    float* prev2 = (float*)alloc((size_t)3 * N * 64 * 4);

    hipMemsetAsync(cnt, 0, (size_t)N * 4, stream);
    hipMemsetAsync(cursor, 0, (size_t)N * 4, stream);

    count_edges<<<(E + 255) / 256, 256, 0, stream>>>(ei, E, cnt);
    compute_dinv<<<(N + 255) / 256, 256, 0, stream>>>(cnt, dinv, N);
    fill_edges<<<(E + 255) / 256, 256, 0, stream>>>(ei, E, dinv, cursor, pairs);
    pad_edges<<<(N + 255) / 256, 256, 0, stream>>>(cnt, pairs, N);
    batch_bounds<<<(N + 255) / 256, 256, 0, stream>>>(batch, N, boff);
    convert_f16<<<(N * 64 + 255) / 256, 256, 0, stream>>>(x, xh, N * 64);

    long nu = (long)N * 64;
    int quads = (N + 3) / 4;                    // blocks of 4 nodes
    int gridA  = quads;                         // phase A: all blocks L1
    int gridBC = ((quads + 1) / 2) * 8;         // 8 XCD slots x ceil(quads/2)

    // ---- phase A: L1 steps 1..8 (snap s=1; diffs s=2,4,8 -> S1 slots 0..2 + S1h) ----
    for (int s = 1; s <= 8; ++s) {
        const float* si = (s == 1) ? x  : ((s & 1) ? b1B : b1A);
        const unsigned short* mi = (s == 1) ? xh : ((s & 1) ? h1B : h1A);
        float* so = (s & 1) ? b1A : b1B;
        unsigned short* mo = (s & 1) ? h1A : h1B;
        cascade1_k<0><<<gridA, 256, 0, stream>>>(
            si, mi, so, mo, prev1, s,
            nullptr, 0, 0, nullptr, 0, nullptr, nullptr, nullptr, 0,
            pairs, cnt, dinv, N, S1, S1h, S2);
    }

    // ---- phase B: role-split — role 0: L1 step t=f+8; roles 1..3: L2 unit, step f ----
    for (int f = 1; f <= 8; ++f) {
        int t = f + 8;
        const float* s1i = ((t - 1) & 1) ? b1A : b1B;
        const unsigned short* m1i = ((t - 1) & 1) ? h1A : h1B;
        float* s1o = (t & 1) ? b1A : b1B;
        unsigned short* m1o = (t & 1) ? h1A : h1B;
        const float* s2i; int sstride2; long usz2;
        const unsigned short* m2i; long musz2;
        if (f == 1) { s2i = S1; sstride2 = 256; usz2 = 64; m2i = S1h; musz2 = nu; }
        else {
            s2i = ((f - 1) & 1) ? b2A : b2B; sstride2 = 64; usz2 = nu;
            m2i = ((f - 1) & 1) ? h2A : h2B; musz2 = nu;
        }
        float* s2o = (f & 1) ? b2A : b2B;
        unsigned short* m2o = (f & 1) ? h2A : h2B;
        cascade1_k<1><<<gridBC, 256, 0, stream>>>(
            s1i, m1i, s1o, m1o, prev1, t,
            s2i, sstride2, usz2, m2i, musz2, s2o, m2o, prev2, f,
            pairs, cnt, dinv, N, S1, S1h, S2);
    }

    // ---- phase C: L2-only steps 9..16, units on XCD slots {3,3,2} ----
    for (int s = 9; s <= 16; ++s) {
        const float* s2i = ((s - 1) & 1) ? b2A : b2B;
        const unsigned short* m2i = ((s - 1) & 1) ? h2A : h2B;
        float* s2o = (s & 1) ? b2A : b2B;
        unsigned short* m2o = (s & 1) ? h2A : h2B;
        cascade1_k<2><<<gridBC, 256, 0, stream>>>(
            nullptr, nullptr, nullptr, nullptr, nullptr, 0,
            s2i, 64, nu, m2i, nu, s2o, m2o, prev2, s,
            pairs, cnt, dinv, N, S1, S1h, S2);
    }

    moments_part<<<NB * 11 * MSLICE, 256, 0, stream>>>(x, S1, S2, boff, part);

    int fin_threads = NB * NFEAT + 68;
    finalize_k<<<(fin_threads + 255) / 256, 256, 0, stream>>>(part, boff, W, out);
}

// Round 4
// 956.947 us; speedup vs baseline: 1.7568x; 1.2019x over previous
//
#include <hip/hip_runtime.h>
#include <hip/hip_fp16.h>

#define NB 8
#define CAP 128
#define NFEAT 704
#define MSLICE 16           // node slices per (batch,k) in moments
#define PSLICE (MSLICE * 4) // partial slots = slices * subs

// ---------------- setup kernels ----------------

__global__ void count_edges(const int* __restrict__ ei, int E, int* __restrict__ cnt) {
    int e = blockIdx.x * blockDim.x + threadIdx.x;
    if (e < E) atomicAdd(&cnt[ei[E + e]], 1);
}

__global__ void compute_dinv(const int* __restrict__ cnt, float* __restrict__ dinv, int n) {
    int v = blockIdx.x * blockDim.x + threadIdx.x;
    if (v < n) dinv[v] = rsqrtf((float)(cnt[v] + 1));  // +1 self-loop; always > 0
}

// packed edge: low 16 = src node (N < 65536), high 16 = f16 weight
__global__ void fill_edges(const int* __restrict__ ei, int E, const float* __restrict__ dinv,
                           int* __restrict__ cursor, unsigned int* __restrict__ pairs) {
    int e = blockIdx.x * blockDim.x + threadIdx.x;
    if (e < E) {
        int r = ei[e], c = ei[E + e];
        int pos = atomicAdd(&cursor[c], 1);
        if (pos < CAP) {
            float w = dinv[r] * dinv[c];
            __half hw = __float2half_rn(w);
            unsigned short hb = *reinterpret_cast<unsigned short*>(&hw);
            pairs[(size_t)c * CAP + pos] = (unsigned int)(r & 0xFFFF) | ((unsigned int)hb << 16);
        }
    }
}

// pad each node's edge list to a multiple of 8 with zero-weight edges (src 0, w +0)
__global__ void pad_edges(const int* __restrict__ cnt, unsigned int* __restrict__ pairs, int n) {
    int v = blockIdx.x * blockDim.x + threadIdx.x;
    if (v >= n) return;
    int c = min(cnt[v], CAP);
    int c8 = (c + 7) & ~7;
    for (int j = c; j < c8; ++j) pairs[(size_t)v * CAP + j] = 0u;
}

// batch is SORTED: boundaries, no atomics
__global__ void batch_bounds(const int* __restrict__ batch, int n, int* __restrict__ boff) {
    int i = blockIdx.x * blockDim.x + threadIdx.x;
    if (i >= n) return;
    int b = batch[i];
    int pb = (i == 0) ? -1 : batch[i - 1];
    for (int k = pb + 1; k <= b; ++k) boff[k] = i;
    if (i == n - 1) {
        for (int k = b + 1; k <= NB; ++k) boff[k] = n;
    }
}

__global__ void convert_f16(const float* __restrict__ x, unsigned short* __restrict__ xh, int n) {
    int i = blockIdx.x * blockDim.x + threadIdx.x;
    if (i < n) {
        __half h = __float2half_rn(x[i]);
        xh[i] = *reinterpret_cast<unsigned short*>(&h);
    }
}

// ---------------- helpers ----------------

__device__ __forceinline__ float h2f16(unsigned short h) {
    __half hh = *reinterpret_cast<__half*>(&h);
    return __half2float(hh);
}

__device__ __forceinline__ unsigned short f2h_bits(float x) {
    __half h = __float2half_rn(x);
    return *reinterpret_cast<unsigned short*>(&h);
}

__device__ __forceinline__ unsigned int pack2(float a, float b) {
    __half2 p = __float22half2_rn(make_float2(a, b));
    return *reinterpret_cast<unsigned int*>(&p);
}

__device__ __forceinline__ void fma_h4(float w, uint2 m, float* a) {
    float2 f0 = __half22float2(*reinterpret_cast<__half2*>(&m.x));
    float2 f1 = __half22float2(*reinterpret_cast<__half2*>(&m.y));
    a[0] += w * f0.x; a[1] += w * f0.y; a[2] += w * f1.x; a[3] += w * f1.y;
}

__device__ __forceinline__ uint2 pack_h4(float4 v) {
    uint2 r;
    r.x = pack2(v.x, v.y);
    r.y = pack2(v.z, v.w);
    return r;
}

// packed fused gather: one uint4 pair = 4 channels x 4 slots of one row
// row layout: half index = ch*4 + slot  (slot0 = L1, slot1+u = L2 unit u)
template <int U1>
__device__ __forceinline__ void fma_pk(float w, uint4 g0, uint4 g1, float a[4][4]) {
    unsigned int lo[4] = {g0.x, g0.z, g1.x, g1.z};   // slots 0,1 per ch
    unsigned int hi[4] = {g0.y, g0.w, g1.y, g1.w};   // slots 2,3 per ch
#pragma unroll
    for (int i = 0; i < 4; ++i) {
        float2 f0 = __half22float2(*reinterpret_cast<__half2*>(&lo[i]));
        float2 f1 = __half22float2(*reinterpret_cast<__half2*>(&hi[i]));
        if (U1) a[0][i] += w * f0.x;
        a[1][i] += w * f0.y;
        a[2][i] += w * f1.x;
        a[3][i] += w * f1.y;
    }
}

// ---------------- phase A: L1-only steps 1..8 (baseline structure) ----------------
// h_out = 0.5*((1+dinv^2)*h_in + sum w*h_in[src]); gathers read fp16 mirror rows
// (128 B/row), 16 lanes/edge (sub=lane>>4 edge phase, cg=lane&15 channel quad).
// Snap s=1; diffs s=2,4,8 -> S1 slots 0..2 (f32) AND packed pk0 slots 1..3 (f16);
// s=8 state -> pk0 slot 0 (the fused phase's L1 gather source).

__global__ __launch_bounds__(256) void cascade_A(
    const float* __restrict__ self1, const unsigned short* __restrict__ mir1,
    float* __restrict__ state1o, unsigned short* __restrict__ mir1o,
    float* __restrict__ prev1, int s1,
    const unsigned int* __restrict__ pairs, const int* __restrict__ cnt,
    const float* __restrict__ dinv, int n,
    float* __restrict__ S1, unsigned short* __restrict__ pk0)
{
    int lane = threadIdx.x & 63, widx = threadIdx.x >> 6;
    int node = blockIdx.x * 4 + widx;
    if (node >= n) return;
    node = __builtin_amdgcn_readfirstlane(node);

    int deg = min(cnt[node], CAP);
    int deg8 = (deg + 7) & ~7;
    float dv = dinv[node];
    float selfw = 1.f + dv * dv;

    int sub = lane >> 4;   // edge within group of 4
    int cg  = lane & 15;   // channel quad

    const unsigned int* pb = pairs + (size_t)node * CAP;
    float a[4] = {0.f, 0.f, 0.f, 0.f};

    if (deg8 > 0) {
        uint4 qA = *reinterpret_cast<const uint4*>(pb);
        uint4 qB = *reinterpret_cast<const uint4*>(pb + 4);
        int j = 0;
        while (true) {
            int jn = j + 8;
            bool more = jn < deg8;
            uint4 nA, nB;
            if (more) {
                nA = *reinterpret_cast<const uint4*>(pb + jn);
                nB = *reinterpret_cast<const uint4*>(pb + jn + 4);
            }
            unsigned int eA = sub < 2 ? (sub == 0 ? qA.x : qA.y) : (sub == 2 ? qA.z : qA.w);
            unsigned int eB = sub < 2 ? (sub == 0 ? qB.x : qB.y) : (sub == 2 ? qB.z : qB.w);
            int   sA = (int)(eA & 0xFFFFu);
            float wA = h2f16((unsigned short)(eA >> 16));
            int   sB = (int)(eB & 0xFFFFu);
            float wB = h2f16((unsigned short)(eB >> 16));
            uint2 gA = *reinterpret_cast<const uint2*>(mir1 + (size_t)sA * 64 + cg * 4);
            uint2 gB = *reinterpret_cast<const uint2*>(mir1 + (size_t)sB * 64 + cg * 4);
            fma_h4(wA, gA, a);
            fma_h4(wB, gB, a);
            if (!more) break;
            qA = nA; qB = nB; j = jn;
        }
    }

#pragma unroll
    for (int m = 16; m <= 32; m <<= 1)
#pragma unroll
        for (int k = 0; k < 4; ++k) a[k] += __shfl_xor(a[k], m, 64);

    if (lane < 16) {
        size_t oidx = (size_t)node * 64 + cg * 4;
        float4 hv = *reinterpret_cast<const float4*>(self1 + oidx);
        float4 v;
        v.x = 0.5f * (selfw * hv.x + a[0]);
        v.y = 0.5f * (selfw * hv.y + a[1]);
        v.z = 0.5f * (selfw * hv.z + a[2]);
        v.w = 0.5f * (selfw * hv.w + a[3]);
        *reinterpret_cast<float4*>(state1o + oidx) = v;
        *reinterpret_cast<uint2*>(mir1o + oidx) = pack_h4(v);
        float* prow = prev1 + oidx;
        if (s1 == 1) {
            *reinterpret_cast<float4*>(prow) = v;
        } else if (s1 == 2 || s1 == 4 || s1 == 8) {
            float4 pv = *reinterpret_cast<const float4*>(prow);
            *reinterpret_cast<float4*>(prow) = v;
            float dd[4];
            dd[0] = fabsf(v.x - pv.x); dd[1] = fabsf(v.y - pv.y);
            dd[2] = fabsf(v.z - pv.z); dd[3] = fabsf(v.w - pv.w);
            int slot = (s1 == 2) ? 0 : (s1 == 4) ? 1 : 2;
            float4 d = make_float4(dd[0], dd[1], dd[2], dd[3]);
            *reinterpret_cast<float4*>(S1 + (size_t)node * 256 + slot * 64 + cg * 4) = d;
            unsigned short* pr = pk0 + (size_t)node * 256 + cg * 16;
#pragma unroll
            for (int i = 0; i < 4; ++i) pr[i * 4 + (slot + 1)] = f2h_bits(dd[i]);
            if (s1 == 8) {
                float vv[4] = {v.x, v.y, v.z, v.w};
#pragma unroll
                for (int i = 0; i < 4; ++i) pr[i * 4 + 0] = f2h_bits(vv[i]);
            }
        }
    }
}

// ---------------- fused cascade on PACKED 4-slot rows ----------------
// U1=1 (phase B): slot0 = L1 step s1=f+8, slots1..3 = L2 units step s2=f.
// U1=0 (phase C): slots1..3 only (slot0 gathered but ignored; written as 0).
// Gather: per edge ONE row base, two uint4 loads (32 B/lane, 512 B/row) —
// half the VMEM instrs and 1/4 the address chains of separate mirrors.
// Epilogue writes the next packed buffer with two contiguous uint4 stores.
// f32 state/prev/S1/S2 paths identical to the 889-us baseline (same numerics).

template <int U1>
__global__ __launch_bounds__(256) void cascade_pk(
    const float* __restrict__ self1, float* __restrict__ state1o,
    float* __restrict__ prev1, int s1,
    const float* __restrict__ self2, int sstride2, long usz2,
    float* __restrict__ state2o, float* __restrict__ prev2, int s2,
    const unsigned short* __restrict__ pkIn, unsigned short* __restrict__ pkOut,
    const unsigned int* __restrict__ pairs, const int* __restrict__ cnt,
    const float* __restrict__ dinv, int n,
    float* __restrict__ S1, float* __restrict__ S2)
{
    int lane = threadIdx.x & 63, widx = threadIdx.x >> 6;
    int node = blockIdx.x * 4 + widx;
    if (node >= n) return;
    node = __builtin_amdgcn_readfirstlane(node);

    int deg = min(cnt[node], CAP);
    int deg8 = (deg + 7) & ~7;
    float dv = dinv[node];
    float selfw = 1.f + dv * dv;

    int sub = lane >> 4;
    int cg  = lane & 15;

    const unsigned int* pb = pairs + (size_t)node * CAP;
    float a[4][4];
#pragma unroll
    for (int s = 0; s < 4; ++s)
#pragma unroll
        for (int k = 0; k < 4; ++k) a[s][k] = 0.f;

    if (deg8 > 0) {
        uint4 qA = *reinterpret_cast<const uint4*>(pb);
        uint4 qB = *reinterpret_cast<const uint4*>(pb + 4);
        int j = 0;
        while (true) {
            int jn = j + 8;
            bool more = jn < deg8;
            uint4 nA, nB;
            if (more) {
                nA = *reinterpret_cast<const uint4*>(pb + jn);
                nB = *reinterpret_cast<const uint4*>(pb + jn + 4);
            }
            unsigned int eA = sub < 2 ? (sub == 0 ? qA.x : qA.y) : (sub == 2 ? qA.z : qA.w);
            unsigned int eB = sub < 2 ? (sub == 0 ? qB.x : qB.y) : (sub == 2 ? qB.z : qB.w);
            int   sA = (int)(eA & 0xFFFFu);
            float wA = h2f16((unsigned short)(eA >> 16));
            int   sB = (int)(eB & 0xFFFFu);
            float wB = h2f16((unsigned short)(eB >> 16));
            const unsigned short* rA = pkIn + (size_t)sA * 256 + cg * 16;
            const unsigned short* rB = pkIn + (size_t)sB * 256 + cg * 16;
            uint4 ga0 = *reinterpret_cast<const uint4*>(rA);
            uint4 ga1 = *reinterpret_cast<const uint4*>(rA + 8);
            uint4 gb0 = *reinterpret_cast<const uint4*>(rB);
            uint4 gb1 = *reinterpret_cast<const uint4*>(rB + 8);
            fma_pk<U1>(wA, ga0, ga1, a);
            fma_pk<U1>(wB, gb0, gb1, a);
            if (!more) break;
            qA = nA; qB = nB; j = jn;
        }
    }

#pragma unroll
    for (int m = 16; m <= 32; m <<= 1) {
#pragma unroll
        for (int s = U1 ? 0 : 1; s < 4; ++s)
#pragma unroll
            for (int k = 0; k < 4; ++k) a[s][k] += __shfl_xor(a[s][k], m, 64);
    }

    if (lane < 16) {
        float vout[4][4];
#pragma unroll
        for (int i = 0; i < 4; ++i) vout[0][i] = 0.f;

        if (U1) {
            size_t oidx = (size_t)node * 64 + cg * 4;
            float4 hv = *reinterpret_cast<const float4*>(self1 + oidx);
            float4 v;
            v.x = 0.5f * (selfw * hv.x + a[0][0]);
            v.y = 0.5f * (selfw * hv.y + a[0][1]);
            v.z = 0.5f * (selfw * hv.z + a[0][2]);
            v.w = 0.5f * (selfw * hv.w + a[0][3]);
            *reinterpret_cast<float4*>(state1o + oidx) = v;
            float* prow = prev1 + oidx;
            if (s1 == 2 || s1 == 4 || s1 == 8 || s1 == 16) {
                float4 pv = *reinterpret_cast<const float4*>(prow);
                *reinterpret_cast<float4*>(prow) = v;
                float4 d;
                d.x = fabsf(v.x - pv.x); d.y = fabsf(v.y - pv.y);
                d.z = fabsf(v.z - pv.z); d.w = fabsf(v.w - pv.w);
                int slot = (s1 == 2) ? 0 : (s1 == 4) ? 1 : (s1 == 8) ? 2 : 3;
                *reinterpret_cast<float4*>(S1 + (size_t)node * 256 + slot * 64 + cg * 4) = d;
            }
            vout[0][0] = v.x; vout[0][1] = v.y; vout[0][2] = v.z; vout[0][3] = v.w;
        }

#pragma unroll
        for (int u = 0; u < 3; ++u) {
            const float* srow = self2 + (size_t)u * usz2 + (size_t)node * sstride2 + cg * 4;
            float4 hv = *reinterpret_cast<const float4*>(srow);
            float4 v;
            v.x = 0.5f * (selfw * hv.x + a[1 + u][0]);
            v.y = 0.5f * (selfw * hv.y + a[1 + u][1]);
            v.z = 0.5f * (selfw * hv.z + a[1 + u][2]);
            v.w = 0.5f * (selfw * hv.w + a[1 + u][3]);
            size_t oidx = (size_t)u * n * 64 + (size_t)node * 64 + cg * 4;
            *reinterpret_cast<float4*>(state2o + oidx) = v;
            int snap = 2 << u;
            float* prow = prev2 + oidx;
            if (s2 == snap) {
                *reinterpret_cast<float4*>(prow) = v;
            } else if (s2 > snap && (s2 == 4 || s2 == 8 || s2 == 16)) {
                float4 pv = *reinterpret_cast<const float4*>(prow);
                *reinterpret_cast<float4*>(prow) = v;
                float4 d;
                d.x = fabsf(v.x - pv.x); d.y = fabsf(v.y - pv.y);
                d.z = fabsf(v.z - pv.z); d.w = fabsf(v.w - pv.w);
                int slt;
                if (u == 0)      slt = (s2 == 4) ? 0 : (s2 == 8) ? 1 : 3;
                else if (u == 1) slt = (s2 == 8) ? 2 : 4;
                else             slt = 5;
                *reinterpret_cast<float4*>(S2 + (size_t)node * 384 + slt * 64 + cg * 4) = d;
            }
            vout[1 + u][0] = v.x; vout[1 + u][1] = v.y;
            vout[1 + u][2] = v.z; vout[1 + u][3] = v.w;
        }

        // packed store: halves [ch*4+slot], lane covers ch cg*4..+3, all slots
        uint4 w0, w1;
        w0.x = pack2(vout[0][0], vout[1][0]); w0.y = pack2(vout[2][0], vout[3][0]);
        w0.z = pack2(vout[0][1], vout[1][1]); w0.w = pack2(vout[2][1], vout[3][1]);
        w1.x = pack2(vout[0][2], vout[1][2]); w1.y = pack2(vout[2][2], vout[3][2]);
        w1.z = pack2(vout[0][3], vout[1][3]); w1.w = pack2(vout[2][3], vout[3][3]);
        unsigned short* po = pkOut + (size_t)node * 256 + cg * 16;
        *reinterpret_cast<uint4*>(po)     = w0;
        *reinterpret_cast<uint4*>(po + 8) = w1;
    }
}

// ---------------- moments (coalesced two-stage, no atomics) ----------------

__global__ __launch_bounds__(256) void moments_part(
    const float* __restrict__ x, const float* __restrict__ S1,
    const float* __restrict__ S2, const int* __restrict__ boff,
    double* __restrict__ part)
{
    int bid = blockIdx.x;                    // b * (11*MSLICE) + k * MSLICE + slice
    int slice = bid % MSLICE;
    int k = (bid / MSLICE) % 11;
    int b = bid / (11 * MSLICE);
    int c = threadIdx.x & 63, sub = threadIdx.x >> 6;

    const float* base; int stride;
    if (k == 0)      { base = x  + c;                stride = 64;  }
    else if (k <= 4) { base = S1 + (k - 1) * 64 + c; stride = 256; }
    else             { base = S2 + (k - 5) * 64 + c; stride = 384; }

    int s0 = boff[b], s1e = boff[b + 1];
    int cntb = s1e - s0;
    int per = (cntb + MSLICE - 1) / MSLICE;
    int i0 = s0 + slice * per;
    int i1 = min(s1e, i0 + per);

    double a1 = 0, a2 = 0, a3 = 0, a4 = 0;
    for (int i = i0 + sub; i < i1; i += 4) {
        double v = (double)base[(size_t)i * stride];
        double qq = v * v;
        a1 += v; a2 += qq; a3 += qq * v; a4 += qq * qq;
    }
    int f = k * 64 + c;
    double* qp = part + ((((size_t)slice * 4 + sub) * NB + b) * NFEAT + f) * 4;
    qp[0] = a1; qp[1] = a2; qp[2] = a3; qp[3] = a4;
}

__global__ void finalize_k(const double* __restrict__ part, const int* __restrict__ boff,
                           const float* __restrict__ W, float* __restrict__ out) {
    int i = blockIdx.x * blockDim.x + threadIdx.x;
    if (i < NB * NFEAT) {
        int b = i / NFEAT, f = i % NFEAT;
        double s1 = 0, s2 = 0, s3 = 0, s4 = 0;
        for (int s = 0; s < PSLICE; ++s) {
            const double* qp = part + (((size_t)s * NB + b) * NFEAT + f) * 4;
            s1 += qp[0]; s2 += qp[1]; s3 += qp[2]; s4 += qp[3];
        }
        double cn = (double)max(boff[b + 1] - boff[b], 1);
        double mean = s1 / cn;
        double e2 = s2 / cn, e3 = s3 / cn, e4 = s4 / cn;
        double var = e2 - mean * mean;
        double m3 = e3 - 3.0 * mean * e2 + 2.0 * mean * mean * mean;
        double m4 = e4 - 4.0 * mean * e3 + 6.0 * mean * mean * e2 - 3.0 * mean * mean * mean * mean;
        float skew, kurt;
        if (var > 0.0) {
            double vs = var * sqrt(var);
            skew = (float)(m3 / vs);
            kurt = (float)(m4 / (var * var));
        } else {
            skew = 0.f; kurt = -3.f;
        }
        out[b * 2816 + f]        = (float)mean;
        out[b * 2816 + 704 + f]  = (float)var;
        out[b * 2816 + 1408 + f] = skew;
        out[b * 2816 + 2112 + f] = kurt;
    } else if (i < NB * NFEAT + 68) {
        int j = i - NB * NFEAT;
        out[NB * 2816 + j] = W[j];
    }
}

// ---------------- launch ----------------

extern "C" void kernel_launch(void* const* d_in, const int* in_sizes, int n_in,
                              void* d_out, int out_size, void* d_ws, size_t ws_size,
                              hipStream_t stream) {
    const float* x     = (const float*)d_in[0];
    const int*   ei    = (const int*)d_in[1];
    const int*   batch = (const int*)d_in[2];
    const float* W     = (const float*)d_in[3];
    int N = in_sizes[0] / 64;   // 20000
    int E = in_sizes[1] / 2;    // 640000
    float* out = (float*)d_out;

    char* p = (char*)d_ws;
    auto alloc = [&](size_t bytes) { char* r = p; p += (bytes + 255) & ~255ULL; return r; };
    float* dinv  = (float*)alloc((size_t)N * 4);
    int*   cnt   = (int*)alloc((size_t)N * 4);
    int*   cursor= (int*)alloc((size_t)N * 4);
    int*   boff  = (int*)alloc((NB + 1) * 4);
    double* part = (double*)alloc((size_t)PSLICE * NB * NFEAT * 4 * 8);
    unsigned int* pairs = (unsigned int*)alloc((size_t)N * CAP * 4);
    float* S1    = (float*)alloc((size_t)N * 256 * 4);
    float* S2    = (float*)alloc((size_t)N * 384 * 4);
    unsigned short* xh  = (unsigned short*)alloc((size_t)N * 64 * 2);
    float* b1A   = (float*)alloc((size_t)N * 64 * 4);
    float* b1B   = (float*)alloc((size_t)N * 64 * 4);
    unsigned short* h1A = (unsigned short*)alloc((size_t)N * 64 * 2);
    unsigned short* h1B = (unsigned short*)alloc((size_t)N * 64 * 2);
    float* prev1 = (float*)alloc((size_t)N * 64 * 4);
    float* b2A   = (float*)alloc((size_t)3 * N * 64 * 4);
    float* b2B   = (float*)alloc((size_t)3 * N * 64 * 4);
    float* prev2 = (float*)alloc((size_t)3 * N * 64 * 4);
    unsigned short* pk0 = (unsigned short*)alloc((size_t)N * 256 * 2);
    unsigned short* pk1 = (unsigned short*)alloc((size_t)N * 256 * 2);

    hipMemsetAsync(cnt, 0, (size_t)N * 4, stream);
    hipMemsetAsync(cursor, 0, (size_t)N * 4, stream);

    count_edges<<<(E + 255) / 256, 256, 0, stream>>>(ei, E, cnt);
    compute_dinv<<<(N + 255) / 256, 256, 0, stream>>>(cnt, dinv, N);
    fill_edges<<<(E + 255) / 256, 256, 0, stream>>>(ei, E, dinv, cursor, pairs);
    pad_edges<<<(N + 255) / 256, 256, 0, stream>>>(cnt, pairs, N);
    batch_bounds<<<(N + 255) / 256, 256, 0, stream>>>(batch, N, boff);
    convert_f16<<<(N * 64 + 255) / 256, 256, 0, stream>>>(x, xh, N * 64);

    long nu = (long)N * 64;
    int cgrid = (N + 3) / 4;

    // ---- phase A: L1 steps 1..8 (fills S1 slots 0..2 + packed pk0) ----
    for (int s = 1; s <= 8; ++s) {
        const float* si = (s == 1) ? x  : ((s & 1) ? b1B : b1A);
        const unsigned short* mi = (s == 1) ? xh : ((s & 1) ? h1B : h1A);
        float* so = (s & 1) ? b1A : b1B;
        unsigned short* mo = (s & 1) ? h1A : h1B;
        cascade_A<<<cgrid, 256, 0, stream>>>(
            si, mi, so, mo, prev1, s,
            pairs, cnt, dinv, N, S1, pk0);
    }

    // ---- phase B: fused — L1 step t=f+8 + 3 L2 units step f, packed gathers ----
    for (int f = 1; f <= 8; ++f) {
        int t = f + 8;
        const float* s1i = ((t - 1) & 1) ? b1A : b1B;
        float* s1o = (t & 1) ? b1A : b1B;
        const float* s2i; int sstride2; long usz2;
        if (f == 1) { s2i = S1; sstride2 = 256; usz2 = 64; }
        else        { s2i = ((f - 1) & 1) ? b2A : b2B; sstride2 = 64; usz2 = nu; }
        float* s2o = (f & 1) ? b2A : b2B;
        const unsigned short* pkI = (f & 1) ? pk0 : pk1;
        unsigned short*       pkO = (f & 1) ? pk1 : pk0;
        cascade_pk<1><<<cgrid, 256, 0, stream>>>(
            s1i, s1o, prev1, t,
            s2i, sstride2, usz2, s2o, prev2, f,
            pkI, pkO, pairs, cnt, dinv, N, S1, S2);
    }

    // ---- phase C: L2-only steps 9..16 (diffs at 16 -> S2 slots 3,4,5) ----
    for (int s = 9; s <= 16; ++s) {
        const float* s2i = ((s - 1) & 1) ? b2A : b2B;
        float* s2o = (s & 1) ? b2A : b2B;
        const unsigned short* pkI = (s & 1) ? pk0 : pk1;
        unsigned short*       pkO = (s & 1) ? pk1 : pk0;
        cascade_pk<0><<<cgrid, 256, 0, stream>>>(
            nullptr, nullptr, nullptr, 0,
            s2i, 64, nu, s2o, prev2, s,
            pkI, pkO, pairs, cnt, dinv, N, S1, S2);
    }

    moments_part<<<NB * 11 * MSLICE, 256, 0, stream>>>(x, S1, S2, boff, part);

    int fin_threads = NB * NFEAT + 68;
    finalize_k<<<(fin_threads + 255) / 256, 256, 0, stream>>>(part, boff, W, out);
}

// Round 6
// 914.367 us; speedup vs baseline: 1.8386x; 1.0466x over previous
//
#include <hip/hip_runtime.h>
#include <hip/hip_fp16.h>

#define NB 8
#define CAP 128
#define NFEAT 704
#define MSLICE 16           // node slices per (batch,k) in moments
#define PSLICE (MSLICE * 4) // partial slots = slices * subs

// ---------------- setup kernels ----------------

__global__ void count_edges(const int* __restrict__ ei, int E, int* __restrict__ cnt) {
    int e = blockIdx.x * blockDim.x + threadIdx.x;
    if (e < E) atomicAdd(&cnt[ei[E + e]], 1);
}

__global__ void compute_dinv(const int* __restrict__ cnt, float* __restrict__ dinv, int n) {
    int v = blockIdx.x * blockDim.x + threadIdx.x;
    if (v < n) dinv[v] = rsqrtf((float)(cnt[v] + 1));  // +1 self-loop; always > 0
}

// packed edge: low 16 = src node (N < 65536), high 16 = f16 weight
__global__ void fill_edges(const int* __restrict__ ei, int E, const float* __restrict__ dinv,
                           int* __restrict__ cursor, unsigned int* __restrict__ pairs) {
    int e = blockIdx.x * blockDim.x + threadIdx.x;
    if (e < E) {
        int r = ei[e], c = ei[E + e];
        int pos = atomicAdd(&cursor[c], 1);
        if (pos < CAP) {
            float w = dinv[r] * dinv[c];
            __half hw = __float2half_rn(w);
            unsigned short hb = *reinterpret_cast<unsigned short*>(&hw);
            pairs[(size_t)c * CAP + pos] = (unsigned int)(r & 0xFFFF) | ((unsigned int)hb << 16);
        }
    }
}

// pad each node's edge list to a multiple of 8 with zero-weight edges (src 0, w +0)
__global__ void pad_edges(const int* __restrict__ cnt, unsigned int* __restrict__ pairs, int n) {
    int v = blockIdx.x * blockDim.x + threadIdx.x;
    if (v >= n) return;
    int c = min(cnt[v], CAP);
    int c8 = (c + 7) & ~7;
    for (int j = c; j < c8; ++j) pairs[(size_t)v * CAP + j] = 0u;
}

// batch is SORTED: boundaries, no atomics
__global__ void batch_bounds(const int* __restrict__ batch, int n, int* __restrict__ boff) {
    int i = blockIdx.x * blockDim.x + threadIdx.x;
    if (i >= n) return;
    int b = batch[i];
    int pb = (i == 0) ? -1 : batch[i - 1];
    for (int k = pb + 1; k <= b; ++k) boff[k] = i;
    if (i == n - 1) {
        for (int k = b + 1; k <= NB; ++k) boff[k] = n;
    }
}

__global__ void convert_f16(const float* __restrict__ x, unsigned short* __restrict__ xh, int n) {
    int i = blockIdx.x * blockDim.x + threadIdx.x;
    if (i < n) {
        __half h = __float2half_rn(x[i]);
        xh[i] = *reinterpret_cast<unsigned short*>(&h);
    }
}

// ---------------- nontemporal helpers (protect gather rows in L2) ----------

typedef unsigned int  u32x4 __attribute__((ext_vector_type(4)));
typedef float         f32x4 __attribute__((ext_vector_type(4)));

__device__ __forceinline__ uint4 ntload_u4(const unsigned int* p) {
    u32x4 t = __builtin_nontemporal_load(reinterpret_cast<const u32x4*>(p));
    uint4 v; v.x = t.x; v.y = t.y; v.z = t.z; v.w = t.w; return v;
}
__device__ __forceinline__ float4 ntload_f4(const float* p) {
    f32x4 t = __builtin_nontemporal_load(reinterpret_cast<const f32x4*>(p));
    return make_float4(t.x, t.y, t.z, t.w);
}
__device__ __forceinline__ void ntstore_f4(float* p, float4 v) {
    f32x4 t; t.x = v.x; t.y = v.y; t.z = v.z; t.w = v.w;
    __builtin_nontemporal_store(t, reinterpret_cast<f32x4*>(p));
}

// ---------------- math helpers ----------------

__device__ __forceinline__ float h2f16(unsigned short h) {
    __half hh = *reinterpret_cast<__half*>(&h);
    return __half2float(hh);
}

__device__ __forceinline__ unsigned short f2h_bits(float x) {
    __half h = __float2half_rn(x);
    return *reinterpret_cast<unsigned short*>(&h);
}

__device__ __forceinline__ unsigned int pack2(float a, float b) {
    __half2 p = __float22half2_rn(make_float2(a, b));
    return *reinterpret_cast<unsigned int*>(&p);
}

__device__ __forceinline__ void fma_h4(float w, uint2 m, float* a) {
    float2 f0 = __half22float2(*reinterpret_cast<__half2*>(&m.x));
    float2 f1 = __half22float2(*reinterpret_cast<__half2*>(&m.y));
    a[0] += w * f0.x; a[1] += w * f0.y; a[2] += w * f1.x; a[3] += w * f1.y;
}

__device__ __forceinline__ uint2 pack_h4(float4 v) {
    uint2 r;
    r.x = pack2(v.x, v.y);
    r.y = pack2(v.z, v.w);
    return r;
}

// 4-slot packed row (512 B): half idx = ch*4 + slot; slot0 = L1, slot1+u = L2 unit u
template <int U1>
__device__ __forceinline__ void fma_pk4(float w, uint4 g0, uint4 g1, float a[4][4]) {
    unsigned int lo[4] = {g0.x, g0.z, g1.x, g1.z};   // slots 0,1 per ch
    unsigned int hi[4] = {g0.y, g0.w, g1.y, g1.w};   // slots 2,3 per ch
#pragma unroll
    for (int i = 0; i < 4; ++i) {
        float2 f0 = __half22float2(*reinterpret_cast<__half2*>(&lo[i]));
        float2 f1 = __half22float2(*reinterpret_cast<__half2*>(&hi[i]));
        if (U1) a[0][i] += w * f0.x;
        a[1][i] += w * f0.y;
        a[2][i] += w * f1.x;
        a[3][i] += w * f1.y;
    }
}

// 3-slot packed row (384 B = 3 lines): s01-plane 256 B (half2 (u0,u1) per ch),
// then s2-plane 128 B (u2 per ch). Lane: uint4 @ cg*16 B, uint2 @ 256+cg*8 B.
__device__ __forceinline__ void fma_pk3(float w, uint4 g4, uint2 g2, float a[4][4]) {
    unsigned int q[4] = {g4.x, g4.y, g4.z, g4.w};
#pragma unroll
    for (int i = 0; i < 4; ++i) {
        float2 f = __half22float2(*reinterpret_cast<__half2*>(&q[i]));
        a[1][i] += w * f.x;
        a[2][i] += w * f.y;
    }
    float2 fa = __half22float2(*reinterpret_cast<__half2*>(&g2.x));
    float2 fb = __half22float2(*reinterpret_cast<__half2*>(&g2.y));
    a[3][0] += w * fa.x; a[3][1] += w * fa.y;
    a[3][2] += w * fb.x; a[3][3] += w * fb.y;
}

// ---------------- phase A: L1-only steps 1..8 ----------------
// Snap s=1; diffs s=2,4,8 -> S1 slots 0..2 (f32) AND packed pk0 slots 1..3 (f16);
// s=8 state -> pk0 slot 0. One-touch streams nontemporal; mirror gathers cached.

__global__ __launch_bounds__(256) void cascade_A(
    const float* __restrict__ self1, const unsigned short* __restrict__ mir1,
    float* __restrict__ state1o, unsigned short* __restrict__ mir1o,
    float* __restrict__ prev1, int s1,
    const unsigned int* __restrict__ pairs, const int* __restrict__ cnt,
    const float* __restrict__ dinv, int n,
    float* __restrict__ S1, unsigned short* __restrict__ pk0)
{
    int lane = threadIdx.x & 63, widx = threadIdx.x >> 6;
    int node = blockIdx.x * 4 + widx;
    if (node >= n) return;
    node = __builtin_amdgcn_readfirstlane(node);

    int deg = min(cnt[node], CAP);
    int deg8 = (deg + 7) & ~7;
    float dv = dinv[node];
    float selfw = 1.f + dv * dv;

    int sub = lane >> 4;   // edge within group of 4
    int cg  = lane & 15;   // channel quad

    const unsigned int* pb = pairs + (size_t)node * CAP;
    float a[4] = {0.f, 0.f, 0.f, 0.f};

    if (deg8 > 0) {
        uint4 qA = ntload_u4(pb);
        uint4 qB = ntload_u4(pb + 4);
        int j = 0;
        while (true) {
            int jn = j + 8;
            bool more = jn < deg8;
            uint4 nA, nB;
            if (more) {
                nA = ntload_u4(pb + jn);
                nB = ntload_u4(pb + jn + 4);
            }
            unsigned int eA = sub < 2 ? (sub == 0 ? qA.x : qA.y) : (sub == 2 ? qA.z : qA.w);
            unsigned int eB = sub < 2 ? (sub == 0 ? qB.x : qB.y) : (sub == 2 ? qB.z : qB.w);
            int   sA = (int)(eA & 0xFFFFu);
            float wA = h2f16((unsigned short)(eA >> 16));
            int   sB = (int)(eB & 0xFFFFu);
            float wB = h2f16((unsigned short)(eB >> 16));
            uint2 gA = *reinterpret_cast<const uint2*>(mir1 + (size_t)sA * 64 + cg * 4);
            uint2 gB = *reinterpret_cast<const uint2*>(mir1 + (size_t)sB * 64 + cg * 4);
            fma_h4(wA, gA, a);
            fma_h4(wB, gB, a);
            if (!more) break;
            qA = nA; qB = nB; j = jn;
        }
    }

#pragma unroll
    for (int m = 16; m <= 32; m <<= 1)
#pragma unroll
        for (int k = 0; k < 4; ++k) a[k] += __shfl_xor(a[k], m, 64);

    if (lane < 16) {
        size_t oidx = (size_t)node * 64 + cg * 4;
        float4 hv = ntload_f4(self1 + oidx);
        float4 v;
        v.x = 0.5f * (selfw * hv.x + a[0]);
        v.y = 0.5f * (selfw * hv.y + a[1]);
        v.z = 0.5f * (selfw * hv.z + a[2]);
        v.w = 0.5f * (selfw * hv.w + a[3]);
        ntstore_f4(state1o + oidx, v);
        *reinterpret_cast<uint2*>(mir1o + oidx) = pack_h4(v);
        float* prow = prev1 + oidx;
        if (s1 == 1) {
            ntstore_f4(prow, v);
        } else if (s1 == 2 || s1 == 4 || s1 == 8) {
            float4 pv = ntload_f4(prow);
            ntstore_f4(prow, v);
            float dd[4];
            dd[0] = fabsf(v.x - pv.x); dd[1] = fabsf(v.y - pv.y);
            dd[2] = fabsf(v.z - pv.z); dd[3] = fabsf(v.w - pv.w);
            int slot = (s1 == 2) ? 0 : (s1 == 4) ? 1 : 2;
            float4 d = make_float4(dd[0], dd[1], dd[2], dd[3]);
            ntstore_f4(S1 + (size_t)node * 256 + slot * 64 + cg * 4, d);
            unsigned short* pr = pk0 + (size_t)node * 256 + cg * 16;
#pragma unroll
            for (int i = 0; i < 4; ++i) pr[i * 4 + (slot + 1)] = f2h_bits(dd[i]);
            if (s1 == 8) {
                float vv[4] = {v.x, v.y, v.z, v.w};
#pragma unroll
                for (int i = 0; i < 4; ++i) pr[i * 4 + 0] = f2h_bits(vv[i]);
            }
        }
    }
}

// ---------------- fused cascade on packed rows ----------------
// <1,0,0> phase B f=1..7: 4-slot in/out (slot0 = L1 step s1=f+8).
// <1,0,1> phase B f=8: 4-slot in, 3-slot out (L1 state dead after t=16).
// <0,1,1> phase C s=9..16: 3-slot in/out (384 B rows, no dead bytes).
// One-touch streams (pairs/self/prev/state/S1/S2) nontemporal; pk gathers and
// pk stores cached. f32 paths identical to the 889-us baseline (same numerics).

template <int U1, int IN3, int OUT3>
__global__ __launch_bounds__(256) void cascade_pk(
    const float* __restrict__ self1, float* __restrict__ state1o,
    float* __restrict__ prev1, int s1,
    const float* __restrict__ self2, int sstride2, long usz2,
    float* __restrict__ state2o, float* __restrict__ prev2, int s2,
    const unsigned short* __restrict__ pkIn, unsigned short* __restrict__ pkOut,
    const unsigned int* __restrict__ pairs, const int* __restrict__ cnt,
    const float* __restrict__ dinv, int n,
    float* __restrict__ S1, float* __restrict__ S2)
{
    int lane = threadIdx.x & 63, widx = threadIdx.x >> 6;
    int node = blockIdx.x * 4 + widx;
    if (node >= n) return;
    node = __builtin_amdgcn_readfirstlane(node);

    int deg = min(cnt[node], CAP);
    int deg8 = (deg + 7) & ~7;
    float dv = dinv[node];
    float selfw = 1.f + dv * dv;

    int sub = lane >> 4;
    int cg  = lane & 15;

    const unsigned int* pb = pairs + (size_t)node * CAP;
    float a[4][4];
#pragma unroll
    for (int s = 0; s < 4; ++s)
#pragma unroll
        for (int k = 0; k < 4; ++k) a[s][k] = 0.f;

    if (deg8 > 0) {
        uint4 qA = ntload_u4(pb);
        uint4 qB = ntload_u4(pb + 4);
        int j = 0;
        while (true) {
            int jn = j + 8;
            bool more = jn < deg8;
            uint4 nA, nB;
            if (more) {
                nA = ntload_u4(pb + jn);
                nB = ntload_u4(pb + jn + 4);
            }
            unsigned int eA = sub < 2 ? (sub == 0 ? qA.x : qA.y) : (sub == 2 ? qA.z : qA.w);
            unsigned int eB = sub < 2 ? (sub == 0 ? qB.x : qB.y) : (sub == 2 ? qB.z : qB.w);
            int   sA = (int)(eA & 0xFFFFu);
            float wA = h2f16((unsigned short)(eA >> 16));
            int   sB = (int)(eB & 0xFFFFu);
            float wB = h2f16((unsigned short)(eB >> 16));
            if (IN3) {
                const unsigned short* rA = pkIn + (size_t)sA * 192;
                const unsigned short* rB = pkIn + (size_t)sB * 192;
                uint4 a4 = *reinterpret_cast<const uint4*>(rA + cg * 8);
                uint2 a2 = *reinterpret_cast<const uint2*>(rA + 128 + cg * 4);
                uint4 b4 = *reinterpret_cast<const uint4*>(rB + cg * 8);
                uint2 b2 = *reinterpret_cast<const uint2*>(rB + 128 + cg * 4);
                fma_pk3(wA, a4, a2, a);
                fma_pk3(wB, b4, b2, a);
            } else {
                const unsigned short* rA = pkIn + (size_t)sA * 256 + cg * 16;
                const unsigned short* rB = pkIn + (size_t)sB * 256 + cg * 16;
                uint4 ga0 = *reinterpret_cast<const uint4*>(rA);
                uint4 ga1 = *reinterpret_cast<const uint4*>(rA + 8);
                uint4 gb0 = *reinterpret_cast<const uint4*>(rB);
                uint4 gb1 = *reinterpret_cast<const uint4*>(rB + 8);
                fma_pk4<U1>(wA, ga0, ga1, a);
                fma_pk4<U1>(wB, gb0, gb1, a);
            }
            if (!more) break;
            qA = nA; qB = nB; j = jn;
        }
    }

#pragma unroll
    for (int m = 16; m <= 32; m <<= 1) {
#pragma unroll
        for (int s = U1 ? 0 : 1; s < 4; ++s)
#pragma unroll
            for (int k = 0; k < 4; ++k) a[s][k] += __shfl_xor(a[s][k], m, 64);
    }

    if (lane < 16) {
        float vout[4][4];
#pragma unroll
        for (int i = 0; i < 4; ++i) vout[0][i] = 0.f;

        if (U1) {
            size_t oidx = (size_t)node * 64 + cg * 4;
            float4 hv = ntload_f4(self1 + oidx);
            float4 v;
            v.x = 0.5f * (selfw * hv.x + a[0][0]);
            v.y = 0.5f * (selfw * hv.y + a[0][1]);
            v.z = 0.5f * (selfw * hv.z + a[0][2]);
            v.w = 0.5f * (selfw * hv.w + a[0][3]);
            ntstore_f4(state1o + oidx, v);
            float* prow = prev1 + oidx;
            if (s1 == 2 || s1 == 4 || s1 == 8 || s1 == 16) {
                float4 pv = ntload_f4(prow);
                ntstore_f4(prow, v);
                float4 d;
                d.x = fabsf(v.x - pv.x); d.y = fabsf(v.y - pv.y);
                d.z = fabsf(v.z - pv.z); d.w = fabsf(v.w - pv.w);
                int slot = (s1 == 2) ? 0 : (s1 == 4) ? 1 : (s1 == 8) ? 2 : 3;
                ntstore_f4(S1 + (size_t)node * 256 + slot * 64 + cg * 4, d);
            }
            vout[0][0] = v.x; vout[0][1] = v.y; vout[0][2] = v.z; vout[0][3] = v.w;
        }

#pragma unroll
        for (int u = 0; u < 3; ++u) {
            const float* srow = self2 + (size_t)u * usz2 + (size_t)node * sstride2 + cg * 4;
            float4 hv = ntload_f4(srow);
            float4 v;
            v.x = 0.5f * (selfw * hv.x + a[1 + u][0]);
            v.y = 0.5f * (selfw * hv.y + a[1 + u][1]);
            v.z = 0.5f * (selfw * hv.z + a[1 + u][2]);
            v.w = 0.5f * (selfw * hv.w + a[1 + u][3]);
            size_t oidx = (size_t)u * n * 64 + (size_t)node * 64 + cg * 4;
            ntstore_f4(state2o + oidx, v);
            int snap = 2 << u;
            float* prow = prev2 + oidx;
            if (s2 == snap) {
                ntstore_f4(prow, v);
            } else if (s2 > snap && (s2 == 4 || s2 == 8 || s2 == 16)) {
                float4 pv = ntload_f4(prow);
                ntstore_f4(prow, v);
                float4 d;
                d.x = fabsf(v.x - pv.x); d.y = fabsf(v.y - pv.y);
                d.z = fabsf(v.z - pv.z); d.w = fabsf(v.w - pv.w);
                int slt;
                if (u == 0)      slt = (s2 == 4) ? 0 : (s2 == 8) ? 1 : 3;
                else if (u == 1) slt = (s2 == 8) ? 2 : 4;
                else             slt = 5;
                ntstore_f4(S2 + (size_t)node * 384 + slt * 64 + cg * 4, d);
            }
            vout[1 + u][0] = v.x; vout[1 + u][1] = v.y;
            vout[1 + u][2] = v.z; vout[1 + u][3] = v.w;
        }

        if (OUT3) {
            unsigned short* po = pkOut + (size_t)node * 192;
            uint4 w4; uint2 w2;
            w4.x = pack2(vout[1][0], vout[2][0]);
            w4.y = pack2(vout[1][1], vout[2][1]);
            w4.z = pack2(vout[1][2], vout[2][2]);
            w4.w = pack2(vout[1][3], vout[2][3]);
            w2.x = pack2(vout[3][0], vout[3][1]);
            w2.y = pack2(vout[3][2], vout[3][3]);
            *reinterpret_cast<uint4*>(po + cg * 8) = w4;
            *reinterpret_cast<uint2*>(po + 128 + cg * 4) = w2;
        } else {
            uint4 w0, w1;
            w0.x = pack2(vout[0][0], vout[1][0]); w0.y = pack2(vout[2][0], vout[3][0]);
            w0.z = pack2(vout[0][1], vout[1][1]); w0.w = pack2(vout[2][1], vout[3][1]);
            w1.x = pack2(vout[0][2], vout[1][2]); w1.y = pack2(vout[2][2], vout[3][2]);
            w1.z = pack2(vout[0][3], vout[1][3]); w1.w = pack2(vout[2][3], vout[3][3]);
            unsigned short* po = pkOut + (size_t)node * 256 + cg * 16;
            *reinterpret_cast<uint4*>(po)     = w0;
            *reinterpret_cast<uint4*>(po + 8) = w1;
        }
    }
}

// ---------------- moments (coalesced two-stage, no atomics) ----------------

__global__ __launch_bounds__(256) void moments_part(
    const float* __restrict__ x, const float* __restrict__ S1,
    const float* __restrict__ S2, const int* __restrict__ boff,
    double* __restrict__ part)
{
    int bid = blockIdx.x;                    // b * (11*MSLICE) + k * MSLICE + slice
    int slice = bid % MSLICE;
    int k = (bid / MSLICE) % 11;
    int b = bid / (11 * MSLICE);
    int c = threadIdx.x & 63, sub = threadIdx.x >> 6;

    const float* base; int stride;
    if (k == 0)      { base = x  + c;                stride = 64;  }
    else if (k <= 4) { base = S1 + (k - 1) * 64 + c; stride = 256; }
    else             { base = S2 + (k - 5) * 64 + c; stride = 384; }

    int s0 = boff[b], s1e = boff[b + 1];
    int cntb = s1e - s0;
    int per = (cntb + MSLICE - 1) / MSLICE;
    int i0 = s0 + slice * per;
    int i1 = min(s1e, i0 + per);

    double a1 = 0, a2 = 0, a3 = 0, a4 = 0;
    for (int i = i0 + sub; i < i1; i += 4) {
        double v = (double)__builtin_nontemporal_load(&base[(size_t)i * stride]);
        double qq = v * v;
        a1 += v; a2 += qq; a3 += qq * v; a4 += qq * qq;
    }
    int f = k * 64 + c;
    double* qp = part + ((((size_t)slice * 4 + sub) * NB + b) * NFEAT + f) * 4;
    qp[0] = a1; qp[1] = a2; qp[2] = a3; qp[3] = a4;
}

__global__ void finalize_k(const double* __restrict__ part, const int* __restrict__ boff,
                           const float* __restrict__ W, float* __restrict__ out) {
    int i = blockIdx.x * blockDim.x + threadIdx.x;
    if (i < NB * NFEAT) {
        int b = i / NFEAT, f = i % NFEAT;
        double s1 = 0, s2 = 0, s3 = 0, s4 = 0;
        for (int s = 0; s < PSLICE; ++s) {
            const double* qp = part + (((size_t)s * NB + b) * NFEAT + f) * 4;
            s1 += qp[0]; s2 += qp[1]; s3 += qp[2]; s4 += qp[3];
        }
        double cn = (double)max(boff[b + 1] - boff[b], 1);
        double mean = s1 / cn;
        double e2 = s2 / cn, e3 = s3 / cn, e4 = s4 / cn;
        double var = e2 - mean * mean;
        double m3 = e3 - 3.0 * mean * e2 + 2.0 * mean * mean * mean;
        double m4 = e4 - 4.0 * mean * e3 + 6.0 * mean * mean * e2 - 3.0 * mean * mean * mean * mean;
        float skew, kurt;
        if (var > 0.0) {
            double vs = var * sqrt(var);
            skew = (float)(m3 / vs);
            kurt = (float)(m4 / (var * var));
        } else {
            skew = 0.f; kurt = -3.f;
        }
        out[b * 2816 + f]        = (float)mean;
        out[b * 2816 + 704 + f]  = (float)var;
        out[b * 2816 + 1408 + f] = skew;
        out[b * 2816 + 2112 + f] = kurt;
    } else if (i < NB * NFEAT + 68) {
        int j = i - NB * NFEAT;
        out[NB * 2816 + j] = W[j];
    }
}

// ---------------- launch ----------------

extern "C" void kernel_launch(void* const* d_in, const int* in_sizes, int n_in,
                              void* d_out, int out_size, void* d_ws, size_t ws_size,
                              hipStream_t stream) {
    const float* x     = (const float*)d_in[0];
    const int*   ei    = (const int*)d_in[1];
    const int*   batch = (const int*)d_in[2];
    const float* W     = (const float*)d_in[3];
    int N = in_sizes[0] / 64;   // 20000
    int E = in_sizes[1] / 2;    // 640000
    float* out = (float*)d_out;

    char* p = (char*)d_ws;
    auto alloc = [&](size_t bytes) { char* r = p; p += (bytes + 255) & ~255ULL; return r; };
    float* dinv  = (float*)alloc((size_t)N * 4);
    int*   cnt   = (int*)alloc((size_t)N * 4);
    int*   cursor= (int*)alloc((size_t)N * 4);
    int*   boff  = (int*)alloc((NB + 1) * 4);
    double* part = (double*)alloc((size_t)PSLICE * NB * NFEAT * 4 * 8);
    unsigned int* pairs = (unsigned int*)alloc((size_t)N * CAP * 4);
    float* S1    = (float*)alloc((size_t)N * 256 * 4);
    float* S2    = (float*)alloc((size_t)N * 384 * 4);
    unsigned short* xh  = (unsigned short*)alloc((size_t)N * 64 * 2);
    float* b1A   = (float*)alloc((size_t)N * 64 * 4);
    float* b1B   = (float*)alloc((size_t)N * 64 * 4);
    unsigned short* h1A = (unsigned short*)alloc((size_t)N * 64 * 2);
    unsigned short* h1B = (unsigned short*)alloc((size_t)N * 64 * 2);
    float* prev1 = (float*)alloc((size_t)N * 64 * 4);
    float* b2A   = (float*)alloc((size_t)3 * N * 64 * 4);
    float* b2B   = (float*)alloc((size_t)3 * N * 64 * 4);
    float* prev2 = (float*)alloc((size_t)3 * N * 64 * 4);
    unsigned short* pk0  = (unsigned short*)alloc((size_t)N * 256 * 2);
    unsigned short* pk1  = (unsigned short*)alloc((size_t)N * 256 * 2);
    unsigned short* pk3A = (unsigned short*)alloc((size_t)N * 192 * 2);
    unsigned short* pk3B = (unsigned short*)alloc((size_t)N * 192 * 2);

    hipMemsetAsync(cnt, 0, (size_t)N * 4, stream);
    hipMemsetAsync(cursor, 0, (size_t)N * 4, stream);

    count_edges<<<(E + 255) / 256, 256, 0, stream>>>(ei, E, cnt);
    compute_dinv<<<(N + 255) / 256, 256, 0, stream>>>(cnt, dinv, N);
    fill_edges<<<(E + 255) / 256, 256, 0, stream>>>(ei, E, dinv, cursor, pairs);
    pad_edges<<<(N + 255) / 256, 256, 0, stream>>>(cnt, pairs, N);
    batch_bounds<<<(N + 255) / 256, 256, 0, stream>>>(batch, N, boff);
    convert_f16<<<(N * 64 + 255) / 256, 256, 0, stream>>>(x, xh, N * 64);

    long nu = (long)N * 64;
    int cgrid = (N + 3) / 4;

    // ---- phase A: L1 steps 1..8 (fills S1 slots 0..2 + packed pk0) ----
    for (int s = 1; s <= 8; ++s) {
        const float* si = (s == 1) ? x  : ((s & 1) ? b1B : b1A);
        const unsigned short* mi = (s == 1) ? xh : ((s & 1) ? h1B : h1A);
        float* so = (s & 1) ? b1A : b1B;
        unsigned short* mo = (s & 1) ? h1A : h1B;
        cascade_A<<<cgrid, 256, 0, stream>>>(
            si, mi, so, mo, prev1, s,
            pairs, cnt, dinv, N, S1, pk0);
    }

    // ---- phase B: fused — L1 step t=f+8 + 3 L2 units step f, packed gathers ----
    for (int f = 1; f <= 8; ++f) {
        int t = f + 8;
        const float* s1i = ((t - 1) & 1) ? b1A : b1B;
        float* s1o = (t & 1) ? b1A : b1B;
        const float* s2i; int sstride2; long usz2;
        if (f == 1) { s2i = S1; sstride2 = 256; usz2 = 64; }
        else        { s2i = ((f - 1) & 1) ? b2A : b2B; sstride2 = 64; usz2 = nu; }
        float* s2o = (f & 1) ? b2A : b2B;
        const unsigned short* pkI = (f & 1) ? pk0 : pk1;
        if (f < 8) {
            unsigned short* pkO = (f & 1) ? pk1 : pk0;
            cascade_pk<1, 0, 0><<<cgrid, 256, 0, stream>>>(
                s1i, s1o, prev1, t,
                s2i, sstride2, usz2, s2o, prev2, f,
                pkI, pkO, pairs, cnt, dinv, N, S1, S2);
        } else {
            cascade_pk<1, 0, 1><<<cgrid, 256, 0, stream>>>(
                s1i, s1o, prev1, t,
                s2i, sstride2, usz2, s2o, prev2, f,
                pkI, pk3A, pairs, cnt, dinv, N, S1, S2);
        }
    }

    // ---- phase C: L2-only steps 9..16 on 3-slot rows (diffs at 16 -> S2 3,4,5) ----
    for (int s = 9; s <= 16; ++s) {
        const float* s2i = ((s - 1) & 1) ? b2A : b2B;
        float* s2o = (s & 1) ? b2A : b2B;
        const unsigned short* pkI = (s & 1) ? pk3A : pk3B;
        unsigned short*       pkO = (s & 1) ? pk3B : pk3A;
        cascade_pk<0, 1, 1><<<cgrid, 256, 0, stream>>>(
            nullptr, nullptr, nullptr, 0,
            s2i, 64, nu, s2o, prev2, s,
            pkI, pkO, pairs, cnt, dinv, N, S1, S2);
    }

    moments_part<<<NB * 11 * MSLICE, 256, 0, stream>>>(x, S1, S2, boff, part);

    int fin_threads = NB * NFEAT + 68;
    finalize_k<<<(fin_threads + 255) / 256, 256, 0, stream>>>(part, boff, W, out);
}